// Round 18
// baseline (423.782 us; speedup 1.0000x reference)
//
#include <hip/hip_runtime.h>

#define SEQ    1024
#define NBAT   4
#define TTOK   4096
#define HIDN   2560
#define NQKV   7680
#define NHEAD  32
#define DHEAD  80
#define NSLOT  8192
#define SCALE_F 0.111803398874989485f   // 80^-0.5
#define LOG2E_F 1.4426950408889634f

typedef float  f32x4  __attribute__((ext_vector_type(4)));
typedef __bf16 bf16x8 __attribute__((ext_vector_type(8)));
typedef short  s16x8  __attribute__((ext_vector_type(8)));
typedef short  s16x4  __attribute__((ext_vector_type(4)));
typedef ushort u16x4  __attribute__((ext_vector_type(4)));

typedef __attribute__((address_space(3))) void lds_v;
typedef __attribute__((address_space(1))) void glb_v;

__device__ __forceinline__ void gload16(const void* g, void* l) {
  __builtin_amdgcn_global_load_lds((glb_v*)g, (lds_v*)l, 16, 0, 0);
}

__device__ __forceinline__ f32x4 mfma16(s16x8 a, s16x8 b, f32x4 c) {
  return __builtin_amdgcn_mfma_f32_16x16x32_bf16(
      __builtin_bit_cast(bf16x8, a), __builtin_bit_cast(bf16x8, b), c, 0, 0, 0);
}

__device__ __forceinline__ ushort f2bf(float f) {
  uint u = __builtin_bit_cast(uint, f);
  u += 0x7fffu + ((u >> 16) & 1u);
  return (ushort)(u >> 16);
}
__device__ __forceinline__ float bf2f(ushort h) {
  uint u = (uint)h << 16;
  return __builtin_bit_cast(float, u);
}

// ------- prep: cvt(hs,qkvw)->bf16 + flags zero ------------------------------
#define NQ_HS  2621440
#define NQ_QW  4915200
#define NQ_DW  1638400
#define NQ_PRE (NQ_HS + NQ_QW)
__global__ __launch_bounds__(256)
void prep_kernel(const float* __restrict__ hs, const float* __restrict__ qkvw,
                 ushort* __restrict__ hsb, ushort* __restrict__ qkvwb,
                 uint* __restrict__ flags) {
  const int tid0 = blockIdx.x * 256 + threadIdx.x;
  if (tid0 < NSLOT) flags[tid0] = 0u;
  const int stride = gridDim.x * 256;
  for (int i = tid0; i < NQ_PRE; i += stride) {
    const float* src; ushort* dst; int q;
    if (i < NQ_HS) { src = hs;   dst = hsb;   q = i; }
    else           { src = qkvw; dst = qkvwb; q = i - NQ_HS; }
    float4 v = *(const float4*)(src + q * 4);
    u16x4 o = { f2bf(v.x), f2bf(v.y), f2bf(v.z), f2bf(v.w) };
    *(u16x4*)(dst + q * 4) = o;
  }
}

// ---------------- 8-phase 256x256 NT GEMM (QKV) — R17 1-barrier, unchanged --
template<int OUT_BF16>
__global__ __launch_bounds__(512, 2)
void gemm8p(const ushort* __restrict__ A, const ushort* __restrict__ B,
            const float* __restrict__ bias, void* __restrict__ Cout,
            int M, int N, int K, int GX, int RR, int RC) {
  __shared__ ushort sA[3][256 * 64];
  __shared__ ushort sB[2][256 * 64];
  const int tid = threadIdx.x;
  const int l   = tid & 63;
  const int w   = tid >> 6;
  const int wm  = w >> 2, wn = w & 3;
  const int r   = l & 15,  g = l >> 4;

  const int fl  = blockIdx.x;
  const int xcd = fl & 7;
  const int idx = fl >> 3;
  const int cgroups = GX / RC;
  const int rg = xcd / cgroups, cg = xcd % cgroups;
  const int by = rg * RR + idx / RC;
  const int bx = cg * RC + idx % RC;
  const int m0  = by * 256, n0 = bx * 256;
  const int NT  = K >> 6;

  const int srow = w * 16 + (l >> 3);
  const int scol = ((l & 7) ^ (l >> 3)) * 8;
  const ushort* Ab = A + (size_t)(m0 + srow) * K + scol;
  const ushort* Bb = B + (size_t)(n0 + srow) * K + scol;
  const size_t r8   = (size_t)8 * K;
  const size_t r128 = (size_t)128 * K;

#define STG_A(t_, h_, buf_) { \
    const ushort* gp = Ab + (size_t)(t_) * 64 + (size_t)(h_) * r128; \
    char* lp = (char*)(&sA[buf_][0]) + ((h_) * 128 + w * 16) * 128; \
    gload16(gp, lp); gload16(gp + r8, lp + 1024); }
#define STG_B(t_, h_, buf_) { \
    const ushort* gp = Bb + (size_t)(t_) * 64 + (size_t)(h_) * r128; \
    char* lp = (char*)(&sB[buf_][0]) + ((h_) * 128 + w * 16) * 128; \
    gload16(gp, lp); gload16(gp + r8, lp + 1024); }

  const int kswz = (r & 7) * 8;
  const int c0 = (g * 8) ^ kswz;
  const int c1 = (32 + g * 8) ^ kswz;
  const int arow = (wm * 128 + r) * 64;
  const int brow = (wn * 64 + r) * 64;

  f32x4 acc[8][4];
#pragma unroll
  for (int m = 0; m < 8; m++)
#pragma unroll
    for (int n = 0; n < 4; n++) { f32x4 z = {0.f,0.f,0.f,0.f}; acc[m][n] = z; }

  STG_A(0, 0, 0); STG_A(0, 1, 0);
  STG_B(0, 0, 0); STG_B(0, 1, 0);
  STG_A(1, 0, 1); STG_A(1, 1, 1);
  asm volatile("s_waitcnt vmcnt(4)" ::: "memory");
  __builtin_amdgcn_sched_barrier(0);
  __builtin_amdgcn_s_barrier();

#define MFMA_Q(q_) \
    __builtin_amdgcn_s_setprio(1); \
    _Pragma("unroll") \
    for (int n = 0; n < 4; n++) acc[2*(q_)  ][n] = mfma16(x0, b0[n], acc[2*(q_)  ][n]); \
    _Pragma("unroll") \
    for (int n = 0; n < 4; n++) acc[2*(q_)+1][n] = mfma16(y0, b0[n], acc[2*(q_)+1][n]); \
    _Pragma("unroll") \
    for (int n = 0; n < 4; n++) acc[2*(q_)  ][n] = mfma16(x1, b1[n], acc[2*(q_)  ][n]); \
    _Pragma("unroll") \
    for (int n = 0; n < 4; n++) acc[2*(q_)+1][n] = mfma16(y1, b1[n], acc[2*(q_)+1][n]); \
    __builtin_amdgcn_s_setprio(0);

#define LOAD_A(m0_, m1_) \
    x0 = *(const s16x8*)&cA[arow + (m0_) * 1024 + c0]; \
    x1 = *(const s16x8*)&cA[arow + (m0_) * 1024 + c1]; \
    y0 = *(const s16x8*)&cA[arow + (m1_) * 1024 + c0]; \
    y1 = *(const s16x8*)&cA[arow + (m1_) * 1024 + c1];

  int bA = 0;
#pragma unroll 1
  for (int t = 0; t < NT; ++t) {
    const ushort* cA = &sA[bA][0];
    const ushort* cB = &sB[t & 1][0];
    const int nb = (t & 1) ^ 1;
    int a2 = bA + 2; if (a2 >= 3) a2 -= 3;

    s16x8 b0[4], b1[4], x0, x1, y0, y1;

#pragma unroll
    for (int n = 0; n < 4; n++) {
      b0[n] = *(const s16x8*)&cB[brow + n * 1024 + c0];
      b1[n] = *(const s16x8*)&cB[brow + n * 1024 + c1];
    }
    LOAD_A(0, 1)
    if (t + 1 < NT) STG_B(t + 1, 0, nb);
    MFMA_Q(0)

    LOAD_A(2, 3)
    if (t + 1 < NT) STG_B(t + 1, 1, nb);
    MFMA_Q(1)

    LOAD_A(4, 5)
    if (t + 2 < NT) STG_A(t + 2, 0, a2);
    MFMA_Q(2)

    LOAD_A(6, 7)
    if (t + 2 < NT) STG_A(t + 2, 1, a2);
    MFMA_Q(3)
    if (t < NT - 2) {
      asm volatile("s_waitcnt vmcnt(4)" ::: "memory");
    } else if (t == NT - 2) {
      asm volatile("s_waitcnt vmcnt(0)" ::: "memory");
    }
    __builtin_amdgcn_sched_barrier(0);
    __builtin_amdgcn_s_barrier();

    bA++; if (bA >= 3) bA = 0;
  }

#pragma unroll
  for (int n = 0; n < 4; n++) {
    const int col = n0 + wn * 64 + n * 16 + r;
    const float bv = bias[col];
#pragma unroll
    for (int m = 0; m < 8; m++) {
      const int row = m0 + wm * 128 + m * 16 + g * 4;
#pragma unroll
      for (int j = 0; j < 4; j++) {
        float v = acc[m][n][j] + bv;
        if (OUT_BF16) ((ushort*)Cout)[(size_t)(row + j) * N + col] = f2bf(v);
        else          ((float*)Cout)[(size_t)(row + j) * N + col] = v;
      }
    }
  }
#undef STG_A
#undef STG_B
#undef MFMA_Q
#undef LOAD_A
}

// ------- dense: 128x128, 4 waves, BK=64, double-buffered, 1 barrier/step ----
// R18: T3-minimum 2-phase. Stage next tile -> compute (16 ds_read + 32 MFMA,
// dep-broken) -> vmcnt(0) AFTER compute -> one barrier. 64KB LDS -> 2 blk/CU.
__global__ __launch_bounds__(256, 2)
void gemm_db(const ushort* __restrict__ A, const ushort* __restrict__ B,
             const float* __restrict__ bias, float* __restrict__ Cout,
             int M, int N, int K, int GX, int RR, int RC) {
  __shared__ ushort sA[2][128 * 64];
  __shared__ ushort sB[2][128 * 64];
  const int tid = threadIdx.x;
  const int l   = tid & 63;
  const int w   = tid >> 6;            // 4 waves
  const int wm  = w >> 1, wn = w & 1;
  const int r   = l & 15,  g = l >> 4;

  const int fl  = blockIdx.x;
  const int xcd = fl & 7;
  const int idx = fl >> 3;
  const int cgroups = GX / RC;
  const int rg = xcd / cgroups, cg = xcd % cgroups;
  const int by = rg * RR + idx / RC;
  const int bx = cg * RC + idx % RC;
  const int m0 = by * 128, n0 = bx * 128;
  const int NT = K >> 6;

  const int srow = w * 16 + (l >> 3);          // 0..63
  const int scol = ((l & 7) ^ (l >> 3)) * 8;   // pre-swizzled
  const ushort* Ab = A + (size_t)(m0 + srow) * K + scol;
  const ushort* Bb = B + (size_t)(n0 + srow) * K + scol;
  const size_t r8  = (size_t)8 * K;
  const size_t r64 = (size_t)64 * K;

#define DSTG_A(t_, h_, buf_) { \
    const ushort* gp = Ab + (size_t)(t_) * 64 + (size_t)(h_) * r64; \
    char* lp = (char*)(&sA[buf_][0]) + ((h_) * 64 + w * 16) * 128; \
    gload16(gp, lp); gload16(gp + r8, lp + 1024); }
#define DSTG_B(t_, h_, buf_) { \
    const ushort* gp = Bb + (size_t)(t_) * 64 + (size_t)(h_) * r64; \
    char* lp = (char*)(&sB[buf_][0]) + ((h_) * 64 + w * 16) * 128; \
    gload16(gp, lp); gload16(gp + r8, lp + 1024); }

  const int kswz = (r & 7) * 8;
  const int c0 = (g * 8) ^ kswz;
  const int c1 = (32 + g * 8) ^ kswz;
  const int arow = (wm * 64 + r) * 64;
  const int brow = (wn * 64 + r) * 64;

  f32x4 acc[4][4];
#pragma unroll
  for (int m = 0; m < 4; m++)
#pragma unroll
    for (int n = 0; n < 4; n++) { f32x4 z = {0.f,0.f,0.f,0.f}; acc[m][n] = z; }

  DSTG_A(0, 0, 0); DSTG_A(0, 1, 0);
  DSTG_B(0, 0, 0); DSTG_B(0, 1, 0);
  asm volatile("s_waitcnt vmcnt(0)" ::: "memory");
  __builtin_amdgcn_sched_barrier(0);
  __builtin_amdgcn_s_barrier();

#pragma unroll 1
  for (int t = 0; t < NT; ++t) {
    const int cur = t & 1, nxt = cur ^ 1;
    const ushort* cA = &sA[cur][0];
    const ushort* cB = &sB[cur][0];

    if (t + 1 < NT) {
      DSTG_A(t + 1, 0, nxt); DSTG_A(t + 1, 1, nxt);
      DSTG_B(t + 1, 0, nxt); DSTG_B(t + 1, 1, nxt);
    }

    s16x8 av[4], aw[4], bv[4], bw[4];
#pragma unroll
    for (int n = 0; n < 4; n++) {
      bv[n] = *(const s16x8*)&cB[brow + n * 1024 + c0];
      bw[n] = *(const s16x8*)&cB[brow + n * 1024 + c1];
    }
#pragma unroll
    for (int m = 0; m < 4; m++) {
      av[m] = *(const s16x8*)&cA[arow + m * 1024 + c0];
      aw[m] = *(const s16x8*)&cA[arow + m * 1024 + c1];
    }
    __builtin_amdgcn_s_setprio(1);
#pragma unroll
    for (int m = 0; m < 4; m++)
#pragma unroll
      for (int n = 0; n < 4; n++)
        acc[m][n] = mfma16(av[m], bv[n], acc[m][n]);   // 16 independent
#pragma unroll
    for (int m = 0; m < 4; m++)
#pragma unroll
      for (int n = 0; n < 4; n++)
        acc[m][n] = mfma16(aw[m], bw[n], acc[m][n]);   // 16 independent
    __builtin_amdgcn_s_setprio(0);

    if (t + 1 < NT) {
      asm volatile("s_waitcnt vmcnt(0)" ::: "memory");
      __builtin_amdgcn_sched_barrier(0);
      __builtin_amdgcn_s_barrier();
    }
  }

#pragma unroll
  for (int n = 0; n < 4; n++) {
    const int col = n0 + wn * 64 + n * 16 + r;
    const float bv2 = bias[col];
#pragma unroll
    for (int m = 0; m < 4; m++) {
      const int row = m0 + wm * 64 + m * 16 + g * 4;
#pragma unroll
      for (int j = 0; j < 4; j++)
        Cout[(size_t)(row + j) * N + col] = acc[m][n][j] + bv2;
    }
  }
#undef DSTG_A
#undef DSTG_B
}

// -------- partial RoPE + KV cache scatter + flag mark — unchanged ----------
__global__ __launch_bounds__(256)
void rope_scatter(ushort* __restrict__ qkv, const float* __restrict__ cosp,
                  const float* __restrict__ sinp, const int* __restrict__ slots,
                  float* __restrict__ kc, float* __restrict__ vc,
                  uint* __restrict__ flags) {
  const int t = blockIdx.x;
  const int tid = threadIdx.x;
  __shared__ float cs[16], sn[16];
  if (tid < 16)       cs[tid]      = cosp[t * 16 + tid];
  else if (tid < 32)  sn[tid - 16] = sinp[t * 16 + tid - 16];
  __syncthreads();
  const int slot = slots[t];
  if (tid == 0) flags[slot] = 1u;
  ushort* qrow = qkv + (size_t)t * NQKV;
  float* kcr = kc + (size_t)slot * HIDN;
  float* vcr = vc + (size_t)slot * HIDN;

  for (int idx = tid; idx < 512; idx += 256) {
    int hh = idx >> 4, i = idx & 15;
    ushort* p = qrow + hh * DHEAD + i;
    float x1 = bf2f(p[0]), x2 = bf2f(p[16]);
    float c = cs[i], s = sn[i];
    p[0]  = f2bf(x1 * c - x2 * s);
    p[16] = f2bf(x1 * s + x2 * c);
  }
  for (int idx = tid; idx < 512; idx += 256) {
    int hh = idx >> 4, i = idx & 15;
    ushort* p = qrow + HIDN + hh * DHEAD + i;
    float x1 = bf2f(p[0]), x2 = bf2f(p[16]);
    float c = cs[i], s = sn[i];
    float k1 = x1 * c - x2 * s, k2 = x1 * s + x2 * c;
    p[0]  = f2bf(k1);
    p[16] = f2bf(k2);
    kcr[hh * DHEAD + i]      = k1;
    kcr[hh * DHEAD + i + 16] = k2;
  }
  for (int idx = tid; idx < 1536; idx += 256) {
    int hh = idx / 48, d = 32 + idx % 48;
    kcr[hh * DHEAD + d] = bf2f(qrow[HIDN + hh * DHEAD + d]);
  }
  for (int idx = tid; idx < HIDN; idx += 256) {
    vcr[idx] = bf2f(qrow[2 * HIDN + idx]);
  }
}

// ---- mega kernel: attn [0,1024) ∥ cache_fill [1024,5120) ∥ densew cvt -----
// R18: attn K/V LDS double-buffered -> end-of-loop sync removed (buf-reuse
// distance 2 guarded by the kept post-write sync; lsP is per-wave-private).
__global__ __launch_bounds__(512, 4)
void mega_kernel(const ushort* __restrict__ qkv, ushort* __restrict__ attn_out,
                 const float* __restrict__ kin, const float* __restrict__ vin,
                 const uint* __restrict__ flags,
                 float* __restrict__ kout, float* __restrict__ vout,
                 const float* __restrict__ densew, ushort* __restrict__ densewb) {
  __shared__ ushort lsK[2][64 * 104];
  __shared__ ushort lsVT[2][80 * 68];
  __shared__ ushort lsP[8][16 * 68];
  const int bid = blockIdx.x;

  if (bid >= 1024) {
    if (bid < 5120) {
      const int row = (bid - 1024) * 2 + (threadIdx.x >> 8);
      const int t2  = threadIdx.x & 255;
      if (flags[row]) return;
      const float4* ks = (const float4*)(kin + (size_t)row * HIDN);
      const float4* vs = (const float4*)(vin + (size_t)row * HIDN);
      float4* kd = (float4*)(kout + (size_t)row * HIDN);
      float4* vd = (float4*)(vout + (size_t)row * HIDN);
      for (int i = t2; i < HIDN / 4; i += 256) { kd[i] = ks[i]; vd[i] = vs[i]; }
    } else {
      int i = (bid - 5120) * 512 + threadIdx.x;
      for (; i < NQ_DW; i += 256 * 512) {
        float4 v = *(const float4*)(densew + i * 4);
        u16x4 o = { f2bf(v.x), f2bf(v.y), f2bf(v.z), f2bf(v.w) };
        *(u16x4*)(densewb + i * 4) = o;
      }
    }
    return;
  }

  const int qb = 7 - (bid >> 7);
  const int hb = bid & 127;
  const int h = hb & 31, b = hb >> 5;
  const int tid  = threadIdx.x;
  const int lane = tid & 63, w = tid >> 6;
  const int r    = lane & 15, g = lane >> 4;

  // zero K pad cols 80..95 in BOTH buffers
  {
    int kv = tid >> 3, cp = tid & 7;
    *(uint*)&lsK[0][kv * 104 + 80 + cp * 2] = 0u;
    *(uint*)&lsK[1][kv * 104 + 80 + cp * 2] = 0u;
  }

  const size_t qrow = (size_t)(b * SEQ + qb * 128 + w * 16 + r);
  const ushort* qp = qkv + qrow * NQKV + h * DHEAD;
  s16x8 qf[3];
  qf[0] = *(const s16x8*)(qp + g * 8);
  qf[1] = *(const s16x8*)(qp + 32 + g * 8);
  if (g < 2) qf[2] = *(const s16x8*)(qp + 64 + g * 8);
  else { s16x8 z = {0,0,0,0,0,0,0,0}; qf[2] = z; }

  int off_g[5]; uint off_kv[5];
#pragma unroll
  for (int j = 0; j < 5; j++) {
    int i = tid + j * 512;
    int kv = i / 40, dp = i - kv * 40;
    off_g[j]  = kv * NQKV + dp * 2;
    off_kv[j] = (uint)(kv * 104 + dp * 2) | ((uint)(dp * 2 * 68 + kv) << 16);
  }
  const ushort* kvbase = qkv + (size_t)(b * SEQ) * NQKV + HIDN + h * DHEAD;

  uint kreg[5], vreg[5];
#pragma unroll
  for (int j = 0; j < 5; j++) {
    kreg[j] = *(const uint*)(kvbase + off_g[j]);
    vreg[j] = *(const uint*)(kvbase + off_g[j] + HIDN);
  }

  float m_run[4] = {-1e30f, -1e30f, -1e30f, -1e30f};
  float l_run[4] = {0.f, 0.f, 0.f, 0.f};
  f32x4 acco[5];
#pragma unroll
  for (int nb = 0; nb < 5; nb++) { f32x4 z = {0.f,0.f,0.f,0.f}; acco[nb] = z; }

  const int ntiles = 2 * qb + 2;
  for (int t = 0; t < ntiles; t++) {
    const int cur = t & 1;
    ushort* curK  = &lsK[cur][0];
    ushort* curVT = &lsVT[cur][0];
#pragma unroll
    for (int j = 0; j < 5; j++) {
      int ok = off_kv[j] & 0xffff, ov = off_kv[j] >> 16;
      *(uint*)&curK[ok] = kreg[j];
      uint vv = vreg[j];
      curVT[ov]      = (ushort)(vv & 0xffffu);
      curVT[ov + 68] = (ushort)(vv >> 16);
    }
    __syncthreads();

    if (t + 1 < ntiles) {
      const ushort* nb_ = kvbase + (size_t)(t + 1) * 64 * NQKV;
#pragma unroll
      for (int j = 0; j < 5; j++) {
        kreg[j] = *(const uint*)(nb_ + off_g[j]);
        vreg[j] = *(const uint*)(nb_ + off_g[j] + HIDN);
      }
    }

    f32x4 sacc[4];
#pragma unroll
    for (int cb = 0; cb < 4; cb++) {
      f32x4 acc = {0.f, 0.f, 0.f, 0.f};
#pragma unroll
      for (int c = 0; c < 3; c++) {
        s16x8 kf = *(const s16x8*)&curK[(cb * 16 + r) * 104 + c * 32 + g * 8];
        acc = mfma16(qf[c], kf, acc);
      }
      sacc[cb] = acc;
    }

    const bool diag = (t >= 2 * qb);
    const int kv0 = t * 64;
    const int q0  = qb * 128 + w * 16 + g * 4;
#pragma unroll
    for (int cb = 0; cb < 4; cb++)
#pragma unroll
      for (int j = 0; j < 4; j++) {
        float s = sacc[cb][j] * SCALE_F;
        if (diag && (kv0 + cb * 16 + r) > (q0 + j)) s = -1e30f;
        sacc[cb][j] = s;
      }

    float mnew[4], alpha[4], rs[4];
#pragma unroll
    for (int j = 0; j < 4; j++) {
      float m = fmaxf(fmaxf(sacc[0][j], sacc[1][j]), fmaxf(sacc[2][j], sacc[3][j]));
      m = fmaxf(m, __shfl_xor(m, 1));
      m = fmaxf(m, __shfl_xor(m, 2));
      m = fmaxf(m, __shfl_xor(m, 4));
      m = fmaxf(m, __shfl_xor(m, 8));
      mnew[j]  = fmaxf(m_run[j], m);
      alpha[j] = exp2f((m_run[j] - mnew[j]) * LOG2E_F);
      m_run[j] = mnew[j];
      rs[j] = 0.f;
    }

#pragma unroll
    for (int cb = 0; cb < 4; cb++)
#pragma unroll
      for (int j = 0; j < 4; j++) {
        float p = exp2f((sacc[cb][j] - mnew[j]) * LOG2E_F);
        rs[j] += p;
        lsP[w][(g * 4 + j) * 68 + cb * 16 + r] = f2bf(p);
      }

#pragma unroll
    for (int j = 0; j < 4; j++) {
      float v = rs[j];
      v += __shfl_xor(v, 1);
      v += __shfl_xor(v, 2);
      v += __shfl_xor(v, 4);
      v += __shfl_xor(v, 8);
      l_run[j] = l_run[j] * alpha[j] + v;
#pragma unroll
      for (int nb = 0; nb < 5; nb++) acco[nb][j] *= alpha[j];
    }

    s16x8 pa[2];
#pragma unroll
    for (int ch = 0; ch < 2; ch++) {
      s16x4 lo = *(const s16x4*)&lsP[w][r * 68 + ch * 32 + g * 8];
      s16x4 hi = *(const s16x4*)&lsP[w][r * 68 + ch * 32 + g * 8 + 4];
      pa[ch] = __builtin_shufflevector(lo, hi, 0, 1, 2, 3, 4, 5, 6, 7);
    }

#pragma unroll
    for (int nb = 0; nb < 5; nb++)
#pragma unroll
      for (int ch = 0; ch < 2; ch++) {
        s16x4 lo = *(const s16x4*)&curVT[(nb * 16 + r) * 68 + ch * 32 + g * 8];
        s16x4 hi = *(const s16x4*)&curVT[(nb * 16 + r) * 68 + ch * 32 + g * 8 + 4];
        s16x8 vf = __builtin_shufflevector(lo, hi, 0, 1, 2, 3, 4, 5, 6, 7);
        acco[nb] = mfma16(pa[ch], vf, acco[nb]);
      }
    // no end-of-loop sync: next iter writes the OTHER K/V buffer; its
    // post-write sync orders buf reuse at distance 2. lsP is per-wave.
  }

  const size_t orow = (size_t)(b * SEQ + qb * 128 + w * 16 + g * 4);
#pragma unroll
  for (int j = 0; j < 4; j++) {
    float inv = 1.0f / l_run[j];
#pragma unroll
    for (int nb = 0; nb < 5; nb++)
      attn_out[(orow + j) * HIDN + h * DHEAD + nb * 16 + r] = f2bf(acco[nb][j] * inv);
  }
}

// ---------------- launch ----------------
extern "C" void kernel_launch(void* const* d_in, const int* in_sizes, int n_in,
                              void* d_out, int out_size, void* d_ws, size_t ws_size,
                              hipStream_t stream) {
  (void)in_sizes; (void)n_in; (void)out_size; (void)ws_size;
  const float* hs      = (const float*)d_in[0];
  const float* cosp    = (const float*)d_in[1];
  const float* sinp    = (const float*)d_in[2];
  const int*   slots   = (const int*)  d_in[3];
  const float* kck_in  = (const float*)d_in[4];
  const float* kcv_in  = (const float*)d_in[5];
  const float* qkvw    = (const float*)d_in[6];
  const float* qkvb    = (const float*)d_in[7];
  const float* densew  = (const float*)d_in[8];
  const float* denseb  = (const float*)d_in[9];

  float* out    = (float*)d_out;
  float* kc_out = out + (size_t)TTOK * HIDN;
  float* vc_out = kc_out + (size_t)NSLOT * HIDN;

  char* ws = (char*)d_ws;
  ushort* hsb     = (ushort*)(ws);
  ushort* attnb   = (ushort*)(ws);               // aliases hsb (dead after gemm8p)
  ushort* qkvwb   = (ushort*)(ws + 20971520);
  ushort* densewb = (ushort*)(ws + 60293120);
  ushort* qkvb16  = (ushort*)(ws + 73400320);
  uint*   flags   = (uint*)(ws + 136314880);

  prep_kernel<<<2048, 256, 0, stream>>>(hs, qkvw, hsb, qkvwb, flags);

  gemm8p<1><<<480, 512, 0, stream>>>(hsb, qkvwb, qkvb, qkvb16, TTOK, NQKV, HIDN, 30, 4, 15);

  rope_scatter<<<TTOK, 256, 0, stream>>>(qkvb16, cosp, sinp, slots, kc_out, vc_out, flags);

  mega_kernel<<<5376, 512, 0, stream>>>(qkvb16, attnb, kck_in, kcv_in, flags,
                                        kc_out, vc_out, densew, densewb);

  // dense: 128^2 dbuf 2-phase; 640 blocks; XCD regions 8 m-tiles x 10 n-tiles
  gemm_db<<<640, 256, 0, stream>>>(
      attnb, densewb, denseb, out, TTOK, HIDN, HIDN, 20, 8, 10);
}

// Round 19
// 421.845 us; speedup vs baseline: 1.0046x; 1.0046x over previous
//
#include <hip/hip_runtime.h>

#define SEQ    1024
#define NBAT   4
#define TTOK   4096
#define HIDN   2560
#define NQKV   7680
#define NHEAD  32
#define DHEAD  80
#define NSLOT  8192
#define SCALE_F 0.111803398874989485f   // 80^-0.5
#define LOG2E_F 1.4426950408889634f

typedef float  f32x4  __attribute__((ext_vector_type(4)));
typedef __bf16 bf16x8 __attribute__((ext_vector_type(8)));
typedef short  s16x8  __attribute__((ext_vector_type(8)));
typedef short  s16x4  __attribute__((ext_vector_type(4)));
typedef ushort u16x4  __attribute__((ext_vector_type(4)));

typedef __attribute__((address_space(3))) void lds_v;
typedef __attribute__((address_space(1))) void glb_v;

__device__ __forceinline__ void gload16(const void* g, void* l) {
  __builtin_amdgcn_global_load_lds((glb_v*)g, (lds_v*)l, 16, 0, 0);
}

__device__ __forceinline__ f32x4 mfma16(s16x8 a, s16x8 b, f32x4 c) {
  return __builtin_amdgcn_mfma_f32_16x16x32_bf16(
      __builtin_bit_cast(bf16x8, a), __builtin_bit_cast(bf16x8, b), c, 0, 0, 0);
}

__device__ __forceinline__ ushort f2bf(float f) {
  uint u = __builtin_bit_cast(uint, f);
  u += 0x7fffu + ((u >> 16) & 1u);
  return (ushort)(u >> 16);
}
__device__ __forceinline__ float bf2f(ushort h) {
  uint u = (uint)h << 16;
  return __builtin_bit_cast(float, u);
}

// ------- prep: cvt(hs,qkvw)->bf16 + flags zero ------------------------------
#define NQ_HS  2621440
#define NQ_QW  4915200
#define NQ_DW  1638400
#define NQ_PRE (NQ_HS + NQ_QW)
__global__ __launch_bounds__(256)
void prep_kernel(const float* __restrict__ hs, const float* __restrict__ qkvw,
                 ushort* __restrict__ hsb, ushort* __restrict__ qkvwb,
                 uint* __restrict__ flags) {
  const int tid0 = blockIdx.x * 256 + threadIdx.x;
  if (tid0 < NSLOT) flags[tid0] = 0u;
  const int stride = gridDim.x * 256;
  for (int i = tid0; i < NQ_PRE; i += stride) {
    const float* src; ushort* dst; int q;
    if (i < NQ_HS) { src = hs;   dst = hsb;   q = i; }
    else           { src = qkvw; dst = qkvwb; q = i - NQ_HS; }
    float4 v = *(const float4*)(src + q * 4);
    u16x4 o = { f2bf(v.x), f2bf(v.y), f2bf(v.z), f2bf(v.w) };
    *(u16x4*)(dst + q * 4) = o;
  }
}

// ---------------- 8-phase 256x256 NT GEMM (QKV) — R17 1-barrier, unchanged --
template<int OUT_BF16>
__global__ __launch_bounds__(512, 2)
void gemm8p(const ushort* __restrict__ A, const ushort* __restrict__ B,
            const float* __restrict__ bias, void* __restrict__ Cout,
            int M, int N, int K, int GX, int RR, int RC) {
  __shared__ ushort sA[3][256 * 64];
  __shared__ ushort sB[2][256 * 64];
  const int tid = threadIdx.x;
  const int l   = tid & 63;
  const int w   = tid >> 6;
  const int wm  = w >> 2, wn = w & 3;
  const int r   = l & 15,  g = l >> 4;

  const int fl  = blockIdx.x;
  const int xcd = fl & 7;
  const int idx = fl >> 3;
  const int cgroups = GX / RC;
  const int rg = xcd / cgroups, cg = xcd % cgroups;
  const int by = rg * RR + idx / RC;
  const int bx = cg * RC + idx % RC;
  const int m0  = by * 256, n0 = bx * 256;
  const int NT  = K >> 6;

  const int srow = w * 16 + (l >> 3);
  const int scol = ((l & 7) ^ (l >> 3)) * 8;
  const ushort* Ab = A + (size_t)(m0 + srow) * K + scol;
  const ushort* Bb = B + (size_t)(n0 + srow) * K + scol;
  const size_t r8   = (size_t)8 * K;
  const size_t r128 = (size_t)128 * K;

#define STG_A(t_, h_, buf_) { \
    const ushort* gp = Ab + (size_t)(t_) * 64 + (size_t)(h_) * r128; \
    char* lp = (char*)(&sA[buf_][0]) + ((h_) * 128 + w * 16) * 128; \
    gload16(gp, lp); gload16(gp + r8, lp + 1024); }
#define STG_B(t_, h_, buf_) { \
    const ushort* gp = Bb + (size_t)(t_) * 64 + (size_t)(h_) * r128; \
    char* lp = (char*)(&sB[buf_][0]) + ((h_) * 128 + w * 16) * 128; \
    gload16(gp, lp); gload16(gp + r8, lp + 1024); }

  const int kswz = (r & 7) * 8;
  const int c0 = (g * 8) ^ kswz;
  const int c1 = (32 + g * 8) ^ kswz;
  const int arow = (wm * 128 + r) * 64;
  const int brow = (wn * 64 + r) * 64;

  f32x4 acc[8][4];
#pragma unroll
  for (int m = 0; m < 8; m++)
#pragma unroll
    for (int n = 0; n < 4; n++) { f32x4 z = {0.f,0.f,0.f,0.f}; acc[m][n] = z; }

  STG_A(0, 0, 0); STG_A(0, 1, 0);
  STG_B(0, 0, 0); STG_B(0, 1, 0);
  STG_A(1, 0, 1); STG_A(1, 1, 1);
  asm volatile("s_waitcnt vmcnt(4)" ::: "memory");
  __builtin_amdgcn_sched_barrier(0);
  __builtin_amdgcn_s_barrier();

#define MFMA_Q(q_) \
    __builtin_amdgcn_s_setprio(1); \
    _Pragma("unroll") \
    for (int n = 0; n < 4; n++) acc[2*(q_)  ][n] = mfma16(x0, b0[n], acc[2*(q_)  ][n]); \
    _Pragma("unroll") \
    for (int n = 0; n < 4; n++) acc[2*(q_)+1][n] = mfma16(y0, b0[n], acc[2*(q_)+1][n]); \
    _Pragma("unroll") \
    for (int n = 0; n < 4; n++) acc[2*(q_)  ][n] = mfma16(x1, b1[n], acc[2*(q_)  ][n]); \
    _Pragma("unroll") \
    for (int n = 0; n < 4; n++) acc[2*(q_)+1][n] = mfma16(y1, b1[n], acc[2*(q_)+1][n]); \
    __builtin_amdgcn_s_setprio(0);

#define LOAD_A(m0_, m1_) \
    x0 = *(const s16x8*)&cA[arow + (m0_) * 1024 + c0]; \
    x1 = *(const s16x8*)&cA[arow + (m0_) * 1024 + c1]; \
    y0 = *(const s16x8*)&cA[arow + (m1_) * 1024 + c0]; \
    y1 = *(const s16x8*)&cA[arow + (m1_) * 1024 + c1];

  int bA = 0;
#pragma unroll 1
  for (int t = 0; t < NT; ++t) {
    const ushort* cA = &sA[bA][0];
    const ushort* cB = &sB[t & 1][0];
    const int nb = (t & 1) ^ 1;
    int a2 = bA + 2; if (a2 >= 3) a2 -= 3;

    s16x8 b0[4], b1[4], x0, x1, y0, y1;

#pragma unroll
    for (int n = 0; n < 4; n++) {
      b0[n] = *(const s16x8*)&cB[brow + n * 1024 + c0];
      b1[n] = *(const s16x8*)&cB[brow + n * 1024 + c1];
    }
    LOAD_A(0, 1)
    if (t + 1 < NT) STG_B(t + 1, 0, nb);
    MFMA_Q(0)

    LOAD_A(2, 3)
    if (t + 1 < NT) STG_B(t + 1, 1, nb);
    MFMA_Q(1)

    LOAD_A(4, 5)
    if (t + 2 < NT) STG_A(t + 2, 0, a2);
    MFMA_Q(2)

    LOAD_A(6, 7)
    if (t + 2 < NT) STG_A(t + 2, 1, a2);
    MFMA_Q(3)
    if (t < NT - 2) {
      asm volatile("s_waitcnt vmcnt(4)" ::: "memory");
    } else if (t == NT - 2) {
      asm volatile("s_waitcnt vmcnt(0)" ::: "memory");
    }
    __builtin_amdgcn_sched_barrier(0);
    __builtin_amdgcn_s_barrier();

    bA++; if (bA >= 3) bA = 0;
  }

#pragma unroll
  for (int n = 0; n < 4; n++) {
    const int col = n0 + wn * 64 + n * 16 + r;
    const float bv = bias[col];
#pragma unroll
    for (int m = 0; m < 8; m++) {
      const int row = m0 + wm * 128 + m * 16 + g * 4;
#pragma unroll
      for (int j = 0; j < 4; j++) {
        float v = acc[m][n][j] + bv;
        if (OUT_BF16) ((ushort*)Cout)[(size_t)(row + j) * N + col] = f2bf(v);
        else          ((float*)Cout)[(size_t)(row + j) * N + col] = v;
      }
    }
  }
#undef STG_A
#undef STG_B
#undef MFMA_Q
#undef LOAD_A
}

// ------- dense: 128x128, 4 waves, BK=64, double-buffered (kept from R18) ----
__global__ __launch_bounds__(256, 2)
void gemm_db(const ushort* __restrict__ A, const ushort* __restrict__ B,
             const float* __restrict__ bias, float* __restrict__ Cout,
             int M, int N, int K, int GX, int RR, int RC) {
  __shared__ ushort sA[2][128 * 64];
  __shared__ ushort sB[2][128 * 64];
  const int tid = threadIdx.x;
  const int l   = tid & 63;
  const int w   = tid >> 6;
  const int wm  = w >> 1, wn = w & 1;
  const int r   = l & 15,  g = l >> 4;

  const int fl  = blockIdx.x;
  const int xcd = fl & 7;
  const int idx = fl >> 3;
  const int cgroups = GX / RC;
  const int rg = xcd / cgroups, cg = xcd % cgroups;
  const int by = rg * RR + idx / RC;
  const int bx = cg * RC + idx % RC;
  const int m0 = by * 128, n0 = bx * 128;
  const int NT = K >> 6;

  const int srow = w * 16 + (l >> 3);
  const int scol = ((l & 7) ^ (l >> 3)) * 8;
  const ushort* Ab = A + (size_t)(m0 + srow) * K + scol;
  const ushort* Bb = B + (size_t)(n0 + srow) * K + scol;
  const size_t r8  = (size_t)8 * K;
  const size_t r64 = (size_t)64 * K;

#define DSTG_A(t_, h_, buf_) { \
    const ushort* gp = Ab + (size_t)(t_) * 64 + (size_t)(h_) * r64; \
    char* lp = (char*)(&sA[buf_][0]) + ((h_) * 64 + w * 16) * 128; \
    gload16(gp, lp); gload16(gp + r8, lp + 1024); }
#define DSTG_B(t_, h_, buf_) { \
    const ushort* gp = Bb + (size_t)(t_) * 64 + (size_t)(h_) * r64; \
    char* lp = (char*)(&sB[buf_][0]) + ((h_) * 64 + w * 16) * 128; \
    gload16(gp, lp); gload16(gp + r8, lp + 1024); }

  const int kswz = (r & 7) * 8;
  const int c0 = (g * 8) ^ kswz;
  const int c1 = (32 + g * 8) ^ kswz;
  const int arow = (wm * 64 + r) * 64;
  const int brow = (wn * 64 + r) * 64;

  f32x4 acc[4][4];
#pragma unroll
  for (int m = 0; m < 4; m++)
#pragma unroll
    for (int n = 0; n < 4; n++) { f32x4 z = {0.f,0.f,0.f,0.f}; acc[m][n] = z; }

  DSTG_A(0, 0, 0); DSTG_A(0, 1, 0);
  DSTG_B(0, 0, 0); DSTG_B(0, 1, 0);
  asm volatile("s_waitcnt vmcnt(0)" ::: "memory");
  __builtin_amdgcn_sched_barrier(0);
  __builtin_amdgcn_s_barrier();

#pragma unroll 1
  for (int t = 0; t < NT; ++t) {
    const int cur = t & 1, nxt = cur ^ 1;
    const ushort* cA = &sA[cur][0];
    const ushort* cB = &sB[cur][0];

    if (t + 1 < NT) {
      DSTG_A(t + 1, 0, nxt); DSTG_A(t + 1, 1, nxt);
      DSTG_B(t + 1, 0, nxt); DSTG_B(t + 1, 1, nxt);
    }

    s16x8 av[4], aw[4], bv[4], bw[4];
#pragma unroll
    for (int n = 0; n < 4; n++) {
      bv[n] = *(const s16x8*)&cB[brow + n * 1024 + c0];
      bw[n] = *(const s16x8*)&cB[brow + n * 1024 + c1];
    }
#pragma unroll
    for (int m = 0; m < 4; m++) {
      av[m] = *(const s16x8*)&cA[arow + m * 1024 + c0];
      aw[m] = *(const s16x8*)&cA[arow + m * 1024 + c1];
    }
    __builtin_amdgcn_s_setprio(1);
#pragma unroll
    for (int m = 0; m < 4; m++)
#pragma unroll
      for (int n = 0; n < 4; n++)
        acc[m][n] = mfma16(av[m], bv[n], acc[m][n]);
#pragma unroll
    for (int m = 0; m < 4; m++)
#pragma unroll
      for (int n = 0; n < 4; n++)
        acc[m][n] = mfma16(aw[m], bw[n], acc[m][n]);
    __builtin_amdgcn_s_setprio(0);

    if (t + 1 < NT) {
      asm volatile("s_waitcnt vmcnt(0)" ::: "memory");
      __builtin_amdgcn_sched_barrier(0);
      __builtin_amdgcn_s_barrier();
    }
  }

#pragma unroll
  for (int n = 0; n < 4; n++) {
    const int col = n0 + wn * 64 + n * 16 + r;
    const float bv2 = bias[col];
#pragma unroll
    for (int m = 0; m < 4; m++) {
      const int row = m0 + wm * 64 + m * 16 + g * 4;
#pragma unroll
      for (int j = 0; j < 4; j++)
        Cout[(size_t)(row + j) * N + col] = acc[m][n][j] + bv2;
    }
  }
#undef DSTG_A
#undef DSTG_B
}

// -------- partial RoPE + KV cache scatter + flag mark — unchanged ----------
__global__ __launch_bounds__(256)
void rope_scatter(ushort* __restrict__ qkv, const float* __restrict__ cosp,
                  const float* __restrict__ sinp, const int* __restrict__ slots,
                  float* __restrict__ kc, float* __restrict__ vc,
                  uint* __restrict__ flags) {
  const int t = blockIdx.x;
  const int tid = threadIdx.x;
  __shared__ float cs[16], sn[16];
  if (tid < 16)       cs[tid]      = cosp[t * 16 + tid];
  else if (tid < 32)  sn[tid - 16] = sinp[t * 16 + tid - 16];
  __syncthreads();
  const int slot = slots[t];
  if (tid == 0) flags[slot] = 1u;
  ushort* qrow = qkv + (size_t)t * NQKV;
  float* kcr = kc + (size_t)slot * HIDN;
  float* vcr = vc + (size_t)slot * HIDN;

  for (int idx = tid; idx < 512; idx += 256) {
    int hh = idx >> 4, i = idx & 15;
    ushort* p = qrow + hh * DHEAD + i;
    float x1 = bf2f(p[0]), x2 = bf2f(p[16]);
    float c = cs[i], s = sn[i];
    p[0]  = f2bf(x1 * c - x2 * s);
    p[16] = f2bf(x1 * s + x2 * c);
  }
  for (int idx = tid; idx < 512; idx += 256) {
    int hh = idx >> 4, i = idx & 15;
    ushort* p = qrow + HIDN + hh * DHEAD + i;
    float x1 = bf2f(p[0]), x2 = bf2f(p[16]);
    float c = cs[i], s = sn[i];
    float k1 = x1 * c - x2 * s, k2 = x1 * s + x2 * c;
    p[0]  = f2bf(k1);
    p[16] = f2bf(k2);
    kcr[hh * DHEAD + i]      = k1;
    kcr[hh * DHEAD + i + 16] = k2;
  }
  for (int idx = tid; idx < 1536; idx += 256) {
    int hh = idx / 48, d = 32 + idx % 48;
    kcr[hh * DHEAD + d] = bf2f(qrow[HIDN + hh * DHEAD + d]);
  }
  for (int idx = tid; idx < HIDN; idx += 256) {
    vcr[idx] = bf2f(qrow[2 * HIDN + idx]);
  }
}

// ---- mega kernel: attn [0,1024) ∥ cache_fill [1024,5120) ∥ densew cvt -----
// R19: attn reverted to SINGLE-buffered K/V (R17 version) — the R18 dbuf
// raised LDS 42->66KB, dropping mega to 2 blocks/CU (occupancy loss on a
// latency-bound kernel was the likely R18 regression).
__global__ __launch_bounds__(512, 4)
void mega_kernel(const ushort* __restrict__ qkv, ushort* __restrict__ attn_out,
                 const float* __restrict__ kin, const float* __restrict__ vin,
                 const uint* __restrict__ flags,
                 float* __restrict__ kout, float* __restrict__ vout,
                 const float* __restrict__ densew, ushort* __restrict__ densewb) {
  __shared__ ushort lsK[64 * 104];
  __shared__ ushort lsVT[80 * 68];
  __shared__ ushort lsP[8][16 * 68];
  const int bid = blockIdx.x;

  if (bid >= 1024) {
    if (bid < 5120) {
      const int row = (bid - 1024) * 2 + (threadIdx.x >> 8);
      const int t2  = threadIdx.x & 255;
      if (flags[row]) return;
      const float4* ks = (const float4*)(kin + (size_t)row * HIDN);
      const float4* vs = (const float4*)(vin + (size_t)row * HIDN);
      float4* kd = (float4*)(kout + (size_t)row * HIDN);
      float4* vd = (float4*)(vout + (size_t)row * HIDN);
      for (int i = t2; i < HIDN / 4; i += 256) { kd[i] = ks[i]; vd[i] = vs[i]; }
    } else {
      int i = (bid - 5120) * 512 + threadIdx.x;
      for (; i < NQ_DW; i += 256 * 512) {
        float4 v = *(const float4*)(densew + i * 4);
        u16x4 o = { f2bf(v.x), f2bf(v.y), f2bf(v.z), f2bf(v.w) };
        *(u16x4*)(densewb + i * 4) = o;
      }
    }
    return;
  }

  const int qb = 7 - (bid >> 7);
  const int hb = bid & 127;
  const int h = hb & 31, b = hb >> 5;
  const int tid  = threadIdx.x;
  const int lane = tid & 63, w = tid >> 6;
  const int r    = lane & 15, g = lane >> 4;

  {
    int kv = tid >> 3, cp = tid & 7;
    *(uint*)&lsK[kv * 104 + 80 + cp * 2] = 0u;
  }

  const size_t qrow = (size_t)(b * SEQ + qb * 128 + w * 16 + r);
  const ushort* qp = qkv + qrow * NQKV + h * DHEAD;
  s16x8 qf[3];
  qf[0] = *(const s16x8*)(qp + g * 8);
  qf[1] = *(const s16x8*)(qp + 32 + g * 8);
  if (g < 2) qf[2] = *(const s16x8*)(qp + 64 + g * 8);
  else { s16x8 z = {0,0,0,0,0,0,0,0}; qf[2] = z; }

  int off_g[5]; uint off_kv[5];
#pragma unroll
  for (int j = 0; j < 5; j++) {
    int i = tid + j * 512;
    int kv = i / 40, dp = i - kv * 40;
    off_g[j]  = kv * NQKV + dp * 2;
    off_kv[j] = (uint)(kv * 104 + dp * 2) | ((uint)(dp * 2 * 68 + kv) << 16);
  }
  const ushort* kvbase = qkv + (size_t)(b * SEQ) * NQKV + HIDN + h * DHEAD;

  uint kreg[5], vreg[5];
#pragma unroll
  for (int j = 0; j < 5; j++) {
    kreg[j] = *(const uint*)(kvbase + off_g[j]);
    vreg[j] = *(const uint*)(kvbase + off_g[j] + HIDN);
  }

  float m_run[4] = {-1e30f, -1e30f, -1e30f, -1e30f};
  float l_run[4] = {0.f, 0.f, 0.f, 0.f};
  f32x4 acco[5];
#pragma unroll
  for (int nb = 0; nb < 5; nb++) { f32x4 z = {0.f,0.f,0.f,0.f}; acco[nb] = z; }

  const int ntiles = 2 * qb + 2;
  for (int t = 0; t < ntiles; t++) {
#pragma unroll
    for (int j = 0; j < 5; j++) {
      int ok = off_kv[j] & 0xffff, ov = off_kv[j] >> 16;
      *(uint*)&lsK[ok] = kreg[j];
      uint vv = vreg[j];
      lsVT[ov]      = (ushort)(vv & 0xffffu);
      lsVT[ov + 68] = (ushort)(vv >> 16);
    }
    __syncthreads();

    if (t + 1 < ntiles) {
      const ushort* nb_ = kvbase + (size_t)(t + 1) * 64 * NQKV;
#pragma unroll
      for (int j = 0; j < 5; j++) {
        kreg[j] = *(const uint*)(nb_ + off_g[j]);
        vreg[j] = *(const uint*)(nb_ + off_g[j] + HIDN);
      }
    }

    f32x4 sacc[4];
#pragma unroll
    for (int cb = 0; cb < 4; cb++) {
      f32x4 acc = {0.f, 0.f, 0.f, 0.f};
#pragma unroll
      for (int c = 0; c < 3; c++) {
        s16x8 kf = *(const s16x8*)&lsK[(cb * 16 + r) * 104 + c * 32 + g * 8];
        acc = mfma16(qf[c], kf, acc);
      }
      sacc[cb] = acc;
    }

    const bool diag = (t >= 2 * qb);
    const int kv0 = t * 64;
    const int q0  = qb * 128 + w * 16 + g * 4;
#pragma unroll
    for (int cb = 0; cb < 4; cb++)
#pragma unroll
      for (int j = 0; j < 4; j++) {
        float s = sacc[cb][j] * SCALE_F;
        if (diag && (kv0 + cb * 16 + r) > (q0 + j)) s = -1e30f;
        sacc[cb][j] = s;
      }

    float mnew[4], alpha[4], rs[4];
#pragma unroll
    for (int j = 0; j < 4; j++) {
      float m = fmaxf(fmaxf(sacc[0][j], sacc[1][j]), fmaxf(sacc[2][j], sacc[3][j]));
      m = fmaxf(m, __shfl_xor(m, 1));
      m = fmaxf(m, __shfl_xor(m, 2));
      m = fmaxf(m, __shfl_xor(m, 4));
      m = fmaxf(m, __shfl_xor(m, 8));
      mnew[j]  = fmaxf(m_run[j], m);
      alpha[j] = exp2f((m_run[j] - mnew[j]) * LOG2E_F);
      m_run[j] = mnew[j];
      rs[j] = 0.f;
    }

#pragma unroll
    for (int cb = 0; cb < 4; cb++)
#pragma unroll
      for (int j = 0; j < 4; j++) {
        float p = exp2f((sacc[cb][j] - mnew[j]) * LOG2E_F);
        rs[j] += p;
        lsP[w][(g * 4 + j) * 68 + cb * 16 + r] = f2bf(p);
      }

#pragma unroll
    for (int j = 0; j < 4; j++) {
      float v = rs[j];
      v += __shfl_xor(v, 1);
      v += __shfl_xor(v, 2);
      v += __shfl_xor(v, 4);
      v += __shfl_xor(v, 8);
      l_run[j] = l_run[j] * alpha[j] + v;
#pragma unroll
      for (int nb = 0; nb < 5; nb++) acco[nb][j] *= alpha[j];
    }

    s16x8 pa[2];
#pragma unroll
    for (int ch = 0; ch < 2; ch++) {
      s16x4 lo = *(const s16x4*)&lsP[w][r * 68 + ch * 32 + g * 8];
      s16x4 hi = *(const s16x4*)&lsP[w][r * 68 + ch * 32 + g * 8 + 4];
      pa[ch] = __builtin_shufflevector(lo, hi, 0, 1, 2, 3, 4, 5, 6, 7);
    }

#pragma unroll
    for (int nb = 0; nb < 5; nb++)
#pragma unroll
      for (int ch = 0; ch < 2; ch++) {
        s16x4 lo = *(const s16x4*)&lsVT[(nb * 16 + r) * 68 + ch * 32 + g * 8];
        s16x4 hi = *(const s16x4*)&lsVT[(nb * 16 + r) * 68 + ch * 32 + g * 8 + 4];
        s16x8 vf = __builtin_shufflevector(lo, hi, 0, 1, 2, 3, 4, 5, 6, 7);
        acco[nb] = mfma16(pa[ch], vf, acco[nb]);
      }

    __syncthreads();
  }

  const size_t orow = (size_t)(b * SEQ + qb * 128 + w * 16 + g * 4);
#pragma unroll
  for (int j = 0; j < 4; j++) {
    float inv = 1.0f / l_run[j];
#pragma unroll
    for (int nb = 0; nb < 5; nb++)
      attn_out[(orow + j) * HIDN + h * DHEAD + nb * 16 + r] = f2bf(acco[nb][j] * inv);
  }
}

// ---------------- launch ----------------
extern "C" void kernel_launch(void* const* d_in, const int* in_sizes, int n_in,
                              void* d_out, int out_size, void* d_ws, size_t ws_size,
                              hipStream_t stream) {
  (void)in_sizes; (void)n_in; (void)out_size; (void)ws_size;
  const float* hs      = (const float*)d_in[0];
  const float* cosp    = (const float*)d_in[1];
  const float* sinp    = (const float*)d_in[2];
  const int*   slots   = (const int*)  d_in[3];
  const float* kck_in  = (const float*)d_in[4];
  const float* kcv_in  = (const float*)d_in[5];
  const float* qkvw    = (const float*)d_in[6];
  const float* qkvb    = (const float*)d_in[7];
  const float* densew  = (const float*)d_in[8];
  const float* denseb  = (const float*)d_in[9];

  float* out    = (float*)d_out;
  float* kc_out = out + (size_t)TTOK * HIDN;
  float* vc_out = kc_out + (size_t)NSLOT * HIDN;

  char* ws = (char*)d_ws;
  ushort* hsb     = (ushort*)(ws);
  ushort* attnb   = (ushort*)(ws);               // aliases hsb (dead after gemm8p)
  ushort* qkvwb   = (ushort*)(ws + 20971520);
  ushort* densewb = (ushort*)(ws + 60293120);
  ushort* qkvb16  = (ushort*)(ws + 73400320);
  uint*   flags   = (uint*)(ws + 136314880);

  prep_kernel<<<2048, 256, 0, stream>>>(hs, qkvw, hsb, qkvwb, flags);

  gemm8p<1><<<480, 512, 0, stream>>>(hsb, qkvwb, qkvb, qkvb16, TTOK, NQKV, HIDN, 30, 4, 15);

  rope_scatter<<<TTOK, 256, 0, stream>>>(qkvb16, cosp, sinp, slots, kc_out, vc_out, flags);

  mega_kernel<<<5376, 512, 0, stream>>>(qkvb16, attnb, kck_in, kcv_in, flags,
                                        kc_out, vc_out, densew, densewb);

  gemm_db<<<640, 256, 0, stream>>>(
      attnb, densewb, denseb, out, TTOK, HIDN, HIDN, 20, 8, 10);
}

// Round 20
// 415.349 us; speedup vs baseline: 1.0203x; 1.0156x over previous
//
#include <hip/hip_runtime.h>

#define SEQ    1024
#define NBAT   4
#define TTOK   4096
#define HIDN   2560
#define NQKV   7680
#define NHEAD  32
#define DHEAD  80
#define NSLOT  8192
#define SCALE_F 0.111803398874989485f   // 80^-0.5
#define LOG2E_F 1.4426950408889634f

typedef float  f32x4  __attribute__((ext_vector_type(4)));
typedef __bf16 bf16x8 __attribute__((ext_vector_type(8)));
typedef short  s16x8  __attribute__((ext_vector_type(8)));
typedef short  s16x4  __attribute__((ext_vector_type(4)));
typedef ushort u16x4  __attribute__((ext_vector_type(4)));

typedef __attribute__((address_space(3))) void lds_v;
typedef __attribute__((address_space(1))) void glb_v;

__device__ __forceinline__ void gload16(const void* g, void* l) {
  __builtin_amdgcn_global_load_lds((glb_v*)g, (lds_v*)l, 16, 0, 0);
}

__device__ __forceinline__ f32x4 mfma16(s16x8 a, s16x8 b, f32x4 c) {
  return __builtin_amdgcn_mfma_f32_16x16x32_bf16(
      __builtin_bit_cast(bf16x8, a), __builtin_bit_cast(bf16x8, b), c, 0, 0, 0);
}

__device__ __forceinline__ ushort f2bf(float f) {
  uint u = __builtin_bit_cast(uint, f);
  u += 0x7fffu + ((u >> 16) & 1u);
  return (ushort)(u >> 16);
}
__device__ __forceinline__ float bf2f(ushort h) {
  uint u = (uint)h << 16;
  return __builtin_bit_cast(float, u);
}

// ------- prep: cvt(hs,qkvw)->bf16 + flags zero ------------------------------
#define NQ_HS  2621440
#define NQ_QW  4915200
#define NQ_DW  1638400
#define NQ_PRE (NQ_HS + NQ_QW)
__global__ __launch_bounds__(256)
void prep_kernel(const float* __restrict__ hs, const float* __restrict__ qkvw,
                 ushort* __restrict__ hsb, ushort* __restrict__ qkvwb,
                 uint* __restrict__ flags) {
  const int tid0 = blockIdx.x * 256 + threadIdx.x;
  if (tid0 < NSLOT) flags[tid0] = 0u;
  const int stride = gridDim.x * 256;
  for (int i = tid0; i < NQ_PRE; i += stride) {
    const float* src; ushort* dst; int q;
    if (i < NQ_HS) { src = hs;   dst = hsb;   q = i; }
    else           { src = qkvw; dst = qkvwb; q = i - NQ_HS; }
    float4 v = *(const float4*)(src + q * 4);
    u16x4 o = { f2bf(v.x), f2bf(v.y), f2bf(v.z), f2bf(v.w) };
    *(u16x4*)(dst + q * 4) = o;
  }
}

// ---------------- 8-phase 256x256 NT GEMM (QKV) — R17 1-barrier, unchanged --
template<int OUT_BF16>
__global__ __launch_bounds__(512, 2)
void gemm8p(const ushort* __restrict__ A, const ushort* __restrict__ B,
            const float* __restrict__ bias, void* __restrict__ Cout,
            int M, int N, int K, int GX, int RR, int RC) {
  __shared__ ushort sA[3][256 * 64];
  __shared__ ushort sB[2][256 * 64];
  const int tid = threadIdx.x;
  const int l   = tid & 63;
  const int w   = tid >> 6;
  const int wm  = w >> 2, wn = w & 3;
  const int r   = l & 15,  g = l >> 4;

  const int fl  = blockIdx.x;
  const int xcd = fl & 7;
  const int idx = fl >> 3;
  const int cgroups = GX / RC;
  const int rg = xcd / cgroups, cg = xcd % cgroups;
  const int by = rg * RR + idx / RC;
  const int bx = cg * RC + idx % RC;
  const int m0  = by * 256, n0 = bx * 256;
  const int NT  = K >> 6;

  const int srow = w * 16 + (l >> 3);
  const int scol = ((l & 7) ^ (l >> 3)) * 8;
  const ushort* Ab = A + (size_t)(m0 + srow) * K + scol;
  const ushort* Bb = B + (size_t)(n0 + srow) * K + scol;
  const size_t r8   = (size_t)8 * K;
  const size_t r128 = (size_t)128 * K;

#define STG_A(t_, h_, buf_) { \
    const ushort* gp = Ab + (size_t)(t_) * 64 + (size_t)(h_) * r128; \
    char* lp = (char*)(&sA[buf_][0]) + ((h_) * 128 + w * 16) * 128; \
    gload16(gp, lp); gload16(gp + r8, lp + 1024); }
#define STG_B(t_, h_, buf_) { \
    const ushort* gp = Bb + (size_t)(t_) * 64 + (size_t)(h_) * r128; \
    char* lp = (char*)(&sB[buf_][0]) + ((h_) * 128 + w * 16) * 128; \
    gload16(gp, lp); gload16(gp + r8, lp + 1024); }

  const int kswz = (r & 7) * 8;
  const int c0 = (g * 8) ^ kswz;
  const int c1 = (32 + g * 8) ^ kswz;
  const int arow = (wm * 128 + r) * 64;
  const int brow = (wn * 64 + r) * 64;

  f32x4 acc[8][4];
#pragma unroll
  for (int m = 0; m < 8; m++)
#pragma unroll
    for (int n = 0; n < 4; n++) { f32x4 z = {0.f,0.f,0.f,0.f}; acc[m][n] = z; }

  STG_A(0, 0, 0); STG_A(0, 1, 0);
  STG_B(0, 0, 0); STG_B(0, 1, 0);
  STG_A(1, 0, 1); STG_A(1, 1, 1);
  asm volatile("s_waitcnt vmcnt(4)" ::: "memory");
  __builtin_amdgcn_sched_barrier(0);
  __builtin_amdgcn_s_barrier();

#define MFMA_Q(q_) \
    __builtin_amdgcn_s_setprio(1); \
    _Pragma("unroll") \
    for (int n = 0; n < 4; n++) acc[2*(q_)  ][n] = mfma16(x0, b0[n], acc[2*(q_)  ][n]); \
    _Pragma("unroll") \
    for (int n = 0; n < 4; n++) acc[2*(q_)+1][n] = mfma16(y0, b0[n], acc[2*(q_)+1][n]); \
    _Pragma("unroll") \
    for (int n = 0; n < 4; n++) acc[2*(q_)  ][n] = mfma16(x1, b1[n], acc[2*(q_)  ][n]); \
    _Pragma("unroll") \
    for (int n = 0; n < 4; n++) acc[2*(q_)+1][n] = mfma16(y1, b1[n], acc[2*(q_)+1][n]); \
    __builtin_amdgcn_s_setprio(0);

#define LOAD_A(m0_, m1_) \
    x0 = *(const s16x8*)&cA[arow + (m0_) * 1024 + c0]; \
    x1 = *(const s16x8*)&cA[arow + (m0_) * 1024 + c1]; \
    y0 = *(const s16x8*)&cA[arow + (m1_) * 1024 + c0]; \
    y1 = *(const s16x8*)&cA[arow + (m1_) * 1024 + c1];

  int bA = 0;
#pragma unroll 1
  for (int t = 0; t < NT; ++t) {
    const ushort* cA = &sA[bA][0];
    const ushort* cB = &sB[t & 1][0];
    const int nb = (t & 1) ^ 1;
    int a2 = bA + 2; if (a2 >= 3) a2 -= 3;

    s16x8 b0[4], b1[4], x0, x1, y0, y1;

#pragma unroll
    for (int n = 0; n < 4; n++) {
      b0[n] = *(const s16x8*)&cB[brow + n * 1024 + c0];
      b1[n] = *(const s16x8*)&cB[brow + n * 1024 + c1];
    }
    LOAD_A(0, 1)
    if (t + 1 < NT) STG_B(t + 1, 0, nb);
    MFMA_Q(0)

    LOAD_A(2, 3)
    if (t + 1 < NT) STG_B(t + 1, 1, nb);
    MFMA_Q(1)

    LOAD_A(4, 5)
    if (t + 2 < NT) STG_A(t + 2, 0, a2);
    MFMA_Q(2)

    LOAD_A(6, 7)
    if (t + 2 < NT) STG_A(t + 2, 1, a2);
    MFMA_Q(3)
    if (t < NT - 2) {
      asm volatile("s_waitcnt vmcnt(4)" ::: "memory");
    } else if (t == NT - 2) {
      asm volatile("s_waitcnt vmcnt(0)" ::: "memory");
    }
    __builtin_amdgcn_sched_barrier(0);
    __builtin_amdgcn_s_barrier();

    bA++; if (bA >= 3) bA = 0;
  }

#pragma unroll
  for (int n = 0; n < 4; n++) {
    const int col = n0 + wn * 64 + n * 16 + r;
    const float bv = bias[col];
#pragma unroll
    for (int m = 0; m < 8; m++) {
      const int row = m0 + wm * 128 + m * 16 + g * 4;
#pragma unroll
      for (int j = 0; j < 4; j++) {
        float v = acc[m][n][j] + bv;
        if (OUT_BF16) ((ushort*)Cout)[(size_t)(row + j) * N + col] = f2bf(v);
        else          ((float*)Cout)[(size_t)(row + j) * N + col] = v;
      }
    }
  }
#undef STG_A
#undef STG_B
#undef MFMA_Q
#undef LOAD_A
}

// ---------------- m97-style 128x128 NT GEMM (dense proj) — restored R17 ----
// R20: gemm_db reverted (R19 isolated it at ~+5 µs vs this kernel).
template<int OUT_BF16>
__global__ __launch_bounds__(256)
void gemm_nt(const ushort* __restrict__ A, const ushort* __restrict__ B,
             const float* __restrict__ bias, void* __restrict__ Cout,
             int M, int N, int K, int GX, int RR, int RC) {
  __shared__ ushort lsA[128 * 32];
  __shared__ ushort lsB[128 * 32];
  const int tid  = threadIdx.x;
  const int lane = tid & 63;
  const int w    = tid >> 6;
  const int wr   = w >> 1, wc = w & 1;
  const int r    = lane & 15, g = lane >> 4;

  const int fl  = blockIdx.x;
  const int xcd = fl & 7;
  const int idx = fl >> 3;
  const int cgroups = GX / RC;
  const int rg = xcd / cgroups, cg = xcd % cgroups;
  const int by = rg * RR + idx / RC;
  const int bx = cg * RC + idx % RC;
  const int m0 = by * 128, n0 = bx * 128;

  const int row0 = tid >> 2;
  const int kc0  = (tid & 3) * 8;

  f32x4 acc[4][4];
#pragma unroll
  for (int i = 0; i < 4; i++)
#pragma unroll
    for (int j = 0; j < 4; j++) { f32x4 z = {0.f,0.f,0.f,0.f}; acc[i][j] = z; }

  const ushort* Abase = A + (size_t)m0 * K;
  const ushort* Bbase = B + (size_t)n0 * K;
  char* dstA0 = (char*)lsA + (size_t)(w * 64) * 16;
  char* dstA1 = (char*)lsA + (size_t)(256 + w * 64) * 16;
  char* dstB0 = (char*)lsB + (size_t)(w * 64) * 16;
  char* dstB1 = (char*)lsB + (size_t)(256 + w * 64) * 16;

  for (int k0 = 0; k0 < K; k0 += 32) {
    gload16(Abase + (size_t)row0 * K + k0 + kc0,        dstA0);
    gload16(Abase + (size_t)(64 + row0) * K + k0 + kc0, dstA1);
    gload16(Bbase + (size_t)row0 * K + k0 + kc0,        dstB0);
    gload16(Bbase + (size_t)(64 + row0) * K + k0 + kc0, dstB1);
    __syncthreads();

    s16x8 af[4], bfr[4];
#pragma unroll
    for (int f = 0; f < 4; f++) {
      af[f]  = *(const s16x8*)&lsA[(wr * 64 + f * 16 + r) * 32 + g * 8];
      bfr[f] = *(const s16x8*)&lsB[(wc * 64 + f * 16 + r) * 32 + g * 8];
    }
#pragma unroll
    for (int fi = 0; fi < 4; fi++)
#pragma unroll
      for (int fj = 0; fj < 4; fj++)
        acc[fi][fj] = mfma16(af[fi], bfr[fj], acc[fi][fj]);
    __syncthreads();
  }

#pragma unroll
  for (int fj = 0; fj < 4; fj++) {
    const int col = n0 + wc * 64 + fj * 16 + r;
    const float bv = bias[col];
#pragma unroll
    for (int fi = 0; fi < 4; fi++) {
      const int row = m0 + wr * 64 + fi * 16 + g * 4;
#pragma unroll
      for (int j = 0; j < 4; j++) {
        float v = acc[fi][fj][j] + bv;
        if (OUT_BF16) ((ushort*)Cout)[(size_t)(row + j) * N + col] = f2bf(v);
        else          ((float*)Cout)[(size_t)(row + j) * N + col] = v;
      }
    }
  }
}

// -------- partial RoPE + KV cache scatter + flag mark — unchanged ----------
__global__ __launch_bounds__(256)
void rope_scatter(ushort* __restrict__ qkv, const float* __restrict__ cosp,
                  const float* __restrict__ sinp, const int* __restrict__ slots,
                  float* __restrict__ kc, float* __restrict__ vc,
                  uint* __restrict__ flags) {
  const int t = blockIdx.x;
  const int tid = threadIdx.x;
  __shared__ float cs[16], sn[16];
  if (tid < 16)       cs[tid]      = cosp[t * 16 + tid];
  else if (tid < 32)  sn[tid - 16] = sinp[t * 16 + tid - 16];
  __syncthreads();
  const int slot = slots[t];
  if (tid == 0) flags[slot] = 1u;
  ushort* qrow = qkv + (size_t)t * NQKV;
  float* kcr = kc + (size_t)slot * HIDN;
  float* vcr = vc + (size_t)slot * HIDN;

  for (int idx = tid; idx < 512; idx += 256) {
    int hh = idx >> 4, i = idx & 15;
    ushort* p = qrow + hh * DHEAD + i;
    float x1 = bf2f(p[0]), x2 = bf2f(p[16]);
    float c = cs[i], s = sn[i];
    p[0]  = f2bf(x1 * c - x2 * s);
    p[16] = f2bf(x1 * s + x2 * c);
  }
  for (int idx = tid; idx < 512; idx += 256) {
    int hh = idx >> 4, i = idx & 15;
    ushort* p = qrow + HIDN + hh * DHEAD + i;
    float x1 = bf2f(p[0]), x2 = bf2f(p[16]);
    float c = cs[i], s = sn[i];
    float k1 = x1 * c - x2 * s, k2 = x1 * s + x2 * c;
    p[0]  = f2bf(k1);
    p[16] = f2bf(k2);
    kcr[hh * DHEAD + i]      = k1;
    kcr[hh * DHEAD + i + 16] = k2;
  }
  for (int idx = tid; idx < 1536; idx += 256) {
    int hh = idx / 48, d = 32 + idx % 48;
    kcr[hh * DHEAD + d] = bf2f(qrow[HIDN + hh * DHEAD + d]);
  }
  for (int idx = tid; idx < HIDN; idx += 256) {
    vcr[idx] = bf2f(qrow[2 * HIDN + idx]);
  }
}

// ---- mega kernel: attn [0,1024) ∥ cache_fill [1024,5120) ∥ densew cvt -----
__global__ __launch_bounds__(512, 4)
void mega_kernel(const ushort* __restrict__ qkv, ushort* __restrict__ attn_out,
                 const float* __restrict__ kin, const float* __restrict__ vin,
                 const uint* __restrict__ flags,
                 float* __restrict__ kout, float* __restrict__ vout,
                 const float* __restrict__ densew, ushort* __restrict__ densewb) {
  __shared__ ushort lsK[64 * 104];
  __shared__ ushort lsVT[80 * 68];
  __shared__ ushort lsP[8][16 * 68];
  const int bid = blockIdx.x;

  if (bid >= 1024) {
    if (bid < 5120) {
      const int row = (bid - 1024) * 2 + (threadIdx.x >> 8);
      const int t2  = threadIdx.x & 255;
      if (flags[row]) return;
      const float4* ks = (const float4*)(kin + (size_t)row * HIDN);
      const float4* vs = (const float4*)(vin + (size_t)row * HIDN);
      float4* kd = (float4*)(kout + (size_t)row * HIDN);
      float4* vd = (float4*)(vout + (size_t)row * HIDN);
      for (int i = t2; i < HIDN / 4; i += 256) { kd[i] = ks[i]; vd[i] = vs[i]; }
    } else {
      int i = (bid - 5120) * 512 + threadIdx.x;
      for (; i < NQ_DW; i += 256 * 512) {
        float4 v = *(const float4*)(densew + i * 4);
        u16x4 o = { f2bf(v.x), f2bf(v.y), f2bf(v.z), f2bf(v.w) };
        *(u16x4*)(densewb + i * 4) = o;
      }
    }
    return;
  }

  const int qb = 7 - (bid >> 7);
  const int hb = bid & 127;
  const int h = hb & 31, b = hb >> 5;
  const int tid  = threadIdx.x;
  const int lane = tid & 63, w = tid >> 6;
  const int r    = lane & 15, g = lane >> 4;

  {
    int kv = tid >> 3, cp = tid & 7;
    *(uint*)&lsK[kv * 104 + 80 + cp * 2] = 0u;
  }

  const size_t qrow = (size_t)(b * SEQ + qb * 128 + w * 16 + r);
  const ushort* qp = qkv + qrow * NQKV + h * DHEAD;
  s16x8 qf[3];
  qf[0] = *(const s16x8*)(qp + g * 8);
  qf[1] = *(const s16x8*)(qp + 32 + g * 8);
  if (g < 2) qf[2] = *(const s16x8*)(qp + 64 + g * 8);
  else { s16x8 z = {0,0,0,0,0,0,0,0}; qf[2] = z; }

  int off_g[5]; uint off_kv[5];
#pragma unroll
  for (int j = 0; j < 5; j++) {
    int i = tid + j * 512;
    int kv = i / 40, dp = i - kv * 40;
    off_g[j]  = kv * NQKV + dp * 2;
    off_kv[j] = (uint)(kv * 104 + dp * 2) | ((uint)(dp * 2 * 68 + kv) << 16);
  }
  const ushort* kvbase = qkv + (size_t)(b * SEQ) * NQKV + HIDN + h * DHEAD;

  uint kreg[5], vreg[5];
#pragma unroll
  for (int j = 0; j < 5; j++) {
    kreg[j] = *(const uint*)(kvbase + off_g[j]);
    vreg[j] = *(const uint*)(kvbase + off_g[j] + HIDN);
  }

  float m_run[4] = {-1e30f, -1e30f, -1e30f, -1e30f};
  float l_run[4] = {0.f, 0.f, 0.f, 0.f};
  f32x4 acco[5];
#pragma unroll
  for (int nb = 0; nb < 5; nb++) { f32x4 z = {0.f,0.f,0.f,0.f}; acco[nb] = z; }

  const int ntiles = 2 * qb + 2;
  for (int t = 0; t < ntiles; t++) {
#pragma unroll
    for (int j = 0; j < 5; j++) {
      int ok = off_kv[j] & 0xffff, ov = off_kv[j] >> 16;
      *(uint*)&lsK[ok] = kreg[j];
      uint vv = vreg[j];
      lsVT[ov]      = (ushort)(vv & 0xffffu);
      lsVT[ov + 68] = (ushort)(vv >> 16);
    }
    __syncthreads();

    if (t + 1 < ntiles) {
      const ushort* nb_ = kvbase + (size_t)(t + 1) * 64 * NQKV;
#pragma unroll
      for (int j = 0; j < 5; j++) {
        kreg[j] = *(const uint*)(nb_ + off_g[j]);
        vreg[j] = *(const uint*)(nb_ + off_g[j] + HIDN);
      }
    }

    f32x4 sacc[4];
#pragma unroll
    for (int cb = 0; cb < 4; cb++) {
      f32x4 acc = {0.f, 0.f, 0.f, 0.f};
#pragma unroll
      for (int c = 0; c < 3; c++) {
        s16x8 kf = *(const s16x8*)&lsK[(cb * 16 + r) * 104 + c * 32 + g * 8];
        acc = mfma16(qf[c], kf, acc);
      }
      sacc[cb] = acc;
    }

    const bool diag = (t >= 2 * qb);
    const int kv0 = t * 64;
    const int q0  = qb * 128 + w * 16 + g * 4;
#pragma unroll
    for (int cb = 0; cb < 4; cb++)
#pragma unroll
      for (int j = 0; j < 4; j++) {
        float s = sacc[cb][j] * SCALE_F;
        if (diag && (kv0 + cb * 16 + r) > (q0 + j)) s = -1e30f;
        sacc[cb][j] = s;
      }

    float mnew[4], alpha[4], rs[4];
#pragma unroll
    for (int j = 0; j < 4; j++) {
      float m = fmaxf(fmaxf(sacc[0][j], sacc[1][j]), fmaxf(sacc[2][j], sacc[3][j]));
      m = fmaxf(m, __shfl_xor(m, 1));
      m = fmaxf(m, __shfl_xor(m, 2));
      m = fmaxf(m, __shfl_xor(m, 4));
      m = fmaxf(m, __shfl_xor(m, 8));
      mnew[j]  = fmaxf(m_run[j], m);
      alpha[j] = exp2f((m_run[j] - mnew[j]) * LOG2E_F);
      m_run[j] = mnew[j];
      rs[j] = 0.f;
    }

#pragma unroll
    for (int cb = 0; cb < 4; cb++)
#pragma unroll
      for (int j = 0; j < 4; j++) {
        float p = exp2f((sacc[cb][j] - mnew[j]) * LOG2E_F);
        rs[j] += p;
        lsP[w][(g * 4 + j) * 68 + cb * 16 + r] = f2bf(p);
      }

#pragma unroll
    for (int j = 0; j < 4; j++) {
      float v = rs[j];
      v += __shfl_xor(v, 1);
      v += __shfl_xor(v, 2);
      v += __shfl_xor(v, 4);
      v += __shfl_xor(v, 8);
      l_run[j] = l_run[j] * alpha[j] + v;
#pragma unroll
      for (int nb = 0; nb < 5; nb++) acco[nb][j] *= alpha[j];
    }

    s16x8 pa[2];
#pragma unroll
    for (int ch = 0; ch < 2; ch++) {
      s16x4 lo = *(const s16x4*)&lsP[w][r * 68 + ch * 32 + g * 8];
      s16x4 hi = *(const s16x4*)&lsP[w][r * 68 + ch * 32 + g * 8 + 4];
      pa[ch] = __builtin_shufflevector(lo, hi, 0, 1, 2, 3, 4, 5, 6, 7);
    }

#pragma unroll
    for (int nb = 0; nb < 5; nb++)
#pragma unroll
      for (int ch = 0; ch < 2; ch++) {
        s16x4 lo = *(const s16x4*)&lsVT[(nb * 16 + r) * 68 + ch * 32 + g * 8];
        s16x4 hi = *(const s16x4*)&lsVT[(nb * 16 + r) * 68 + ch * 32 + g * 8 + 4];
        s16x8 vf = __builtin_shufflevector(lo, hi, 0, 1, 2, 3, 4, 5, 6, 7);
        acco[nb] = mfma16(pa[ch], vf, acco[nb]);
      }

    __syncthreads();
  }

  const size_t orow = (size_t)(b * SEQ + qb * 128 + w * 16 + g * 4);
#pragma unroll
  for (int j = 0; j < 4; j++) {
    float inv = 1.0f / l_run[j];
#pragma unroll
    for (int nb = 0; nb < 5; nb++)
      attn_out[(orow + j) * HIDN + h * DHEAD + nb * 16 + r] = f2bf(acco[nb][j] * inv);
  }
}

// ---------------- launch ----------------
extern "C" void kernel_launch(void* const* d_in, const int* in_sizes, int n_in,
                              void* d_out, int out_size, void* d_ws, size_t ws_size,
                              hipStream_t stream) {
  (void)in_sizes; (void)n_in; (void)out_size; (void)ws_size;
  const float* hs      = (const float*)d_in[0];
  const float* cosp    = (const float*)d_in[1];
  const float* sinp    = (const float*)d_in[2];
  const int*   slots   = (const int*)  d_in[3];
  const float* kck_in  = (const float*)d_in[4];
  const float* kcv_in  = (const float*)d_in[5];
  const float* qkvw    = (const float*)d_in[6];
  const float* qkvb    = (const float*)d_in[7];
  const float* densew  = (const float*)d_in[8];
  const float* denseb  = (const float*)d_in[9];

  float* out    = (float*)d_out;
  float* kc_out = out + (size_t)TTOK * HIDN;
  float* vc_out = kc_out + (size_t)NSLOT * HIDN;

  char* ws = (char*)d_ws;
  ushort* hsb     = (ushort*)(ws);
  ushort* attnb   = (ushort*)(ws);               // aliases hsb (dead after gemm8p)
  ushort* qkvwb   = (ushort*)(ws + 20971520);
  ushort* densewb = (ushort*)(ws + 60293120);
  ushort* qkvb16  = (ushort*)(ws + 73400320);
  uint*   flags   = (uint*)(ws + 136314880);

  prep_kernel<<<2048, 256, 0, stream>>>(hs, qkvw, hsb, qkvwb, flags);

  gemm8p<1><<<480, 512, 0, stream>>>(hsb, qkvwb, qkvb, qkvb16, TTOK, NQKV, HIDN, 30, 4, 15);

  rope_scatter<<<TTOK, 256, 0, stream>>>(qkvb16, cosp, sinp, slots, kc_out, vc_out, flags);

  mega_kernel<<<5376, 512, 0, stream>>>(qkvb16, attnb, kck_in, kcv_in, flags,
                                        kc_out, vc_out, densew, densewb);

  gemm_nt<0><<<640, 256, 0, stream>>>(
      attnb, densewb, denseb, out, TTOK, HIDN, HIDN, 20, 8, 10);
}

// Round 21
// 404.026 us; speedup vs baseline: 1.0489x; 1.0280x over previous
//
#include <hip/hip_runtime.h>

#define SEQ    1024
#define NBAT   4
#define TTOK   4096
#define HIDN   2560
#define NQKV   7680
#define NHEAD  32
#define DHEAD  80
#define NSLOT  8192
#define SCALE_F 0.111803398874989485f   // 80^-0.5
#define LOG2E_F 1.4426950408889634f

typedef float  f32x4  __attribute__((ext_vector_type(4)));
typedef __bf16 bf16x8 __attribute__((ext_vector_type(8)));
typedef short  s16x8  __attribute__((ext_vector_type(8)));
typedef short  s16x4  __attribute__((ext_vector_type(4)));
typedef ushort u16x4  __attribute__((ext_vector_type(4)));

typedef __attribute__((address_space(3))) void lds_v;
typedef __attribute__((address_space(1))) void glb_v;

__device__ __forceinline__ void gload16(const void* g, void* l) {
  __builtin_amdgcn_global_load_lds((glb_v*)g, (lds_v*)l, 16, 0, 0);
}

__device__ __forceinline__ f32x4 mfma16(s16x8 a, s16x8 b, f32x4 c) {
  return __builtin_amdgcn_mfma_f32_16x16x32_bf16(
      __builtin_bit_cast(bf16x8, a), __builtin_bit_cast(bf16x8, b), c, 0, 0, 0);
}

__device__ __forceinline__ ushort f2bf(float f) {
  uint u = __builtin_bit_cast(uint, f);
  u += 0x7fffu + ((u >> 16) & 1u);
  return (ushort)(u >> 16);
}
__device__ __forceinline__ float bf2f(ushort h) {
  uint u = (uint)h << 16;
  return __builtin_bit_cast(float, u);
}

// ------- prep: cvt(hs,qkvw)->bf16 + flags zero ------------------------------
#define NQ_HS  2621440
#define NQ_QW  4915200
#define NQ_DW  1638400
#define NQ_PRE (NQ_HS + NQ_QW)
__global__ __launch_bounds__(256)
void prep_kernel(const float* __restrict__ hs, const float* __restrict__ qkvw,
                 ushort* __restrict__ hsb, ushort* __restrict__ qkvwb,
                 uint* __restrict__ flags) {
  const int tid0 = blockIdx.x * 256 + threadIdx.x;
  if (tid0 < NSLOT) flags[tid0] = 0u;
  const int stride = gridDim.x * 256;
  for (int i = tid0; i < NQ_PRE; i += stride) {
    const float* src; ushort* dst; int q;
    if (i < NQ_HS) { src = hs;   dst = hsb;   q = i; }
    else           { src = qkvw; dst = qkvwb; q = i - NQ_HS; }
    float4 v = *(const float4*)(src + q * 4);
    u16x4 o = { f2bf(v.x), f2bf(v.y), f2bf(v.z), f2bf(v.w) };
    *(u16x4*)(dst + q * 4) = o;
  }
}

// ---------------- 8-phase 256x256 NT GEMM (QKV) — R17 1-barrier, unchanged --
template<int OUT_BF16>
__global__ __launch_bounds__(512, 2)
void gemm8p(const ushort* __restrict__ A, const ushort* __restrict__ B,
            const float* __restrict__ bias, void* __restrict__ Cout,
            int M, int N, int K, int GX, int RR, int RC) {
  __shared__ ushort sA[3][256 * 64];
  __shared__ ushort sB[2][256 * 64];
  const int tid = threadIdx.x;
  const int l   = tid & 63;
  const int w   = tid >> 6;
  const int wm  = w >> 2, wn = w & 3;
  const int r   = l & 15,  g = l >> 4;

  const int fl  = blockIdx.x;
  const int xcd = fl & 7;
  const int idx = fl >> 3;
  const int cgroups = GX / RC;
  const int rg = xcd / cgroups, cg = xcd % cgroups;
  const int by = rg * RR + idx / RC;
  const int bx = cg * RC + idx % RC;
  const int m0  = by * 256, n0 = bx * 256;
  const int NT  = K >> 6;

  const int srow = w * 16 + (l >> 3);
  const int scol = ((l & 7) ^ (l >> 3)) * 8;
  const ushort* Ab = A + (size_t)(m0 + srow) * K + scol;
  const ushort* Bb = B + (size_t)(n0 + srow) * K + scol;
  const size_t r8   = (size_t)8 * K;
  const size_t r128 = (size_t)128 * K;

#define STG_A(t_, h_, buf_) { \
    const ushort* gp = Ab + (size_t)(t_) * 64 + (size_t)(h_) * r128; \
    char* lp = (char*)(&sA[buf_][0]) + ((h_) * 128 + w * 16) * 128; \
    gload16(gp, lp); gload16(gp + r8, lp + 1024); }
#define STG_B(t_, h_, buf_) { \
    const ushort* gp = Bb + (size_t)(t_) * 64 + (size_t)(h_) * r128; \
    char* lp = (char*)(&sB[buf_][0]) + ((h_) * 128 + w * 16) * 128; \
    gload16(gp, lp); gload16(gp + r8, lp + 1024); }

  const int kswz = (r & 7) * 8;
  const int c0 = (g * 8) ^ kswz;
  const int c1 = (32 + g * 8) ^ kswz;
  const int arow = (wm * 128 + r) * 64;
  const int brow = (wn * 64 + r) * 64;

  f32x4 acc[8][4];
#pragma unroll
  for (int m = 0; m < 8; m++)
#pragma unroll
    for (int n = 0; n < 4; n++) { f32x4 z = {0.f,0.f,0.f,0.f}; acc[m][n] = z; }

  STG_A(0, 0, 0); STG_A(0, 1, 0);
  STG_B(0, 0, 0); STG_B(0, 1, 0);
  STG_A(1, 0, 1); STG_A(1, 1, 1);
  asm volatile("s_waitcnt vmcnt(4)" ::: "memory");
  __builtin_amdgcn_sched_barrier(0);
  __builtin_amdgcn_s_barrier();

#define MFMA_Q(q_) \
    __builtin_amdgcn_s_setprio(1); \
    _Pragma("unroll") \
    for (int n = 0; n < 4; n++) acc[2*(q_)  ][n] = mfma16(x0, b0[n], acc[2*(q_)  ][n]); \
    _Pragma("unroll") \
    for (int n = 0; n < 4; n++) acc[2*(q_)+1][n] = mfma16(y0, b0[n], acc[2*(q_)+1][n]); \
    _Pragma("unroll") \
    for (int n = 0; n < 4; n++) acc[2*(q_)  ][n] = mfma16(x1, b1[n], acc[2*(q_)  ][n]); \
    _Pragma("unroll") \
    for (int n = 0; n < 4; n++) acc[2*(q_)+1][n] = mfma16(y1, b1[n], acc[2*(q_)+1][n]); \
    __builtin_amdgcn_s_setprio(0);

#define LOAD_A(m0_, m1_) \
    x0 = *(const s16x8*)&cA[arow + (m0_) * 1024 + c0]; \
    x1 = *(const s16x8*)&cA[arow + (m0_) * 1024 + c1]; \
    y0 = *(const s16x8*)&cA[arow + (m1_) * 1024 + c0]; \
    y1 = *(const s16x8*)&cA[arow + (m1_) * 1024 + c1];

  int bA = 0;
#pragma unroll 1
  for (int t = 0; t < NT; ++t) {
    const ushort* cA = &sA[bA][0];
    const ushort* cB = &sB[t & 1][0];
    const int nb = (t & 1) ^ 1;
    int a2 = bA + 2; if (a2 >= 3) a2 -= 3;

    s16x8 b0[4], b1[4], x0, x1, y0, y1;

#pragma unroll
    for (int n = 0; n < 4; n++) {
      b0[n] = *(const s16x8*)&cB[brow + n * 1024 + c0];
      b1[n] = *(const s16x8*)&cB[brow + n * 1024 + c1];
    }
    LOAD_A(0, 1)
    if (t + 1 < NT) STG_B(t + 1, 0, nb);
    MFMA_Q(0)

    LOAD_A(2, 3)
    if (t + 1 < NT) STG_B(t + 1, 1, nb);
    MFMA_Q(1)

    LOAD_A(4, 5)
    if (t + 2 < NT) STG_A(t + 2, 0, a2);
    MFMA_Q(2)

    LOAD_A(6, 7)
    if (t + 2 < NT) STG_A(t + 2, 1, a2);
    MFMA_Q(3)
    if (t < NT - 2) {
      asm volatile("s_waitcnt vmcnt(4)" ::: "memory");
    } else if (t == NT - 2) {
      asm volatile("s_waitcnt vmcnt(0)" ::: "memory");
    }
    __builtin_amdgcn_sched_barrier(0);
    __builtin_amdgcn_s_barrier();

    bA++; if (bA >= 3) bA = 0;
  }

#pragma unroll
  for (int n = 0; n < 4; n++) {
    const int col = n0 + wn * 64 + n * 16 + r;
    const float bv = bias[col];
#pragma unroll
    for (int m = 0; m < 8; m++) {
      const int row = m0 + wm * 128 + m * 16 + g * 4;
#pragma unroll
      for (int j = 0; j < 4; j++) {
        float v = acc[m][n][j] + bv;
        if (OUT_BF16) ((ushort*)Cout)[(size_t)(row + j) * N + col] = f2bf(v);
        else          ((float*)Cout)[(size_t)(row + j) * N + col] = v;
      }
    }
  }
#undef STG_A
#undef STG_B
#undef MFMA_Q
#undef LOAD_A
}

// ------- dense: 128x128, 4 waves, BK=32, DOUBLE-buffered, 1 barrier/step ----
// R21: applies the R16/R17 barrier-reduction to dense. 32KB LDS keeps ~5
// blocks/CU (gemm_db's failure was 2 blk/CU at BK=64). 80 barriers (was 160).
// Slot-XOR swizzle (slot ^= row&3): 8-way read conflict -> 4-way.
__global__ __launch_bounds__(256)
void gemm_db32(const ushort* __restrict__ A, const ushort* __restrict__ B,
               const float* __restrict__ bias, float* __restrict__ Cout,
               int M, int N, int K, int GX, int RR, int RC) {
  __shared__ ushort sA[2][128 * 32];   // 8KB each
  __shared__ ushort sB[2][128 * 32];
  const int tid = threadIdx.x;
  const int l   = tid & 63;
  const int w   = tid >> 6;            // 0..3
  const int wm  = w >> 1, wn = w & 1;
  const int r   = l & 15,  g = l >> 4; // g in 0..3

  const int fl  = blockIdx.x;
  const int xcd = fl & 7;
  const int idx = fl >> 3;
  const int cgroups = GX / RC;
  const int rg = xcd / cgroups, cg = xcd % cgroups;
  const int by = rg * RR + idx / RC;
  const int bx = cg * RC + idx % RC;
  const int m0 = by * 128, n0 = bx * 128;
  const int NT = K >> 5;               // 80

  // staging: half h covers rows h*64 + (tid>>2); slot tid&3; source slot
  // pre-swizzled by row&3 (LDS dest stays linear: byte = w*1024 + lane*16).
  const int srow  = tid >> 2;                       // 0..63
  const int sslot = (tid & 3) ^ (srow & 3);         // pre-swizzled k-slot
  const ushort* Ab = A + (size_t)(m0 + srow) * K + sslot * 8;
  const ushort* Bb = B + (size_t)(n0 + srow) * K + sslot * 8;
  const size_t r64 = (size_t)64 * K;

#define DSTG_A(t_, h_, buf_) { \
    const ushort* gp = Ab + (size_t)(t_) * 32 + (size_t)(h_) * r64; \
    char* lp = (char*)(&sA[buf_][0]) + ((h_) * 64 + srow) * 64 + (tid & 3) * 16; \
    gload16(gp, lp); }
#define DSTG_B(t_, h_, buf_) { \
    const ushort* gp = Bb + (size_t)(t_) * 32 + (size_t)(h_) * r64; \
    char* lp = (char*)(&sB[buf_][0]) + ((h_) * 64 + srow) * 64 + (tid & 3) * 16; \
    gload16(gp, lp); }

  // read: global (row, slot g) lives at LDS slot g ^ (row&3); row&3 == r&3.
  const int cslot = (g ^ (r & 3)) * 8;
  const int arow = (wm * 64 + r) * 32;
  const int brow = (wn * 64 + r) * 32;

  f32x4 acc[4][4];
#pragma unroll
  for (int m = 0; m < 4; m++)
#pragma unroll
    for (int n = 0; n < 4; n++) { f32x4 z = {0.f,0.f,0.f,0.f}; acc[m][n] = z; }

  DSTG_A(0, 0, 0); DSTG_A(0, 1, 0);
  DSTG_B(0, 0, 0); DSTG_B(0, 1, 0);
  asm volatile("s_waitcnt vmcnt(0)" ::: "memory");
  __builtin_amdgcn_sched_barrier(0);
  __builtin_amdgcn_s_barrier();

#pragma unroll 1
  for (int t = 0; t < NT; ++t) {
    const int cur = t & 1, nxt = cur ^ 1;
    const ushort* cA = &sA[cur][0];
    const ushort* cB = &sB[cur][0];

    if (t + 1 < NT) {
      DSTG_A(t + 1, 0, nxt); DSTG_A(t + 1, 1, nxt);
      DSTG_B(t + 1, 0, nxt); DSTG_B(t + 1, 1, nxt);
    }

    s16x8 av[4], bfr[4];
#pragma unroll
    for (int n = 0; n < 4; n++)
      bfr[n] = *(const s16x8*)&cB[brow + n * 512 + cslot];
#pragma unroll
    for (int m = 0; m < 4; m++)
      av[m] = *(const s16x8*)&cA[arow + m * 512 + cslot];

    __builtin_amdgcn_s_setprio(1);
#pragma unroll
    for (int m = 0; m < 4; m++)
#pragma unroll
      for (int n = 0; n < 4; n++)
        acc[m][n] = mfma16(av[m], bfr[n], acc[m][n]);   // 16 independent
    __builtin_amdgcn_s_setprio(0);

    if (t + 1 < NT) {
      asm volatile("s_waitcnt vmcnt(0)" ::: "memory");
      __builtin_amdgcn_sched_barrier(0);
      __builtin_amdgcn_s_barrier();
    }
  }

#pragma unroll
  for (int n = 0; n < 4; n++) {
    const int col = n0 + wn * 64 + n * 16 + r;
    const float bv = bias[col];
#pragma unroll
    for (int m = 0; m < 4; m++) {
      const int row = m0 + wm * 64 + m * 16 + g * 4;
#pragma unroll
      for (int j = 0; j < 4; j++)
        Cout[(size_t)(row + j) * N + col] = acc[m][n][j] + bv;
    }
  }
#undef DSTG_A
#undef DSTG_B
}

// -------- partial RoPE + KV cache scatter + flag mark — unchanged ----------
__global__ __launch_bounds__(256)
void rope_scatter(ushort* __restrict__ qkv, const float* __restrict__ cosp,
                  const float* __restrict__ sinp, const int* __restrict__ slots,
                  float* __restrict__ kc, float* __restrict__ vc,
                  uint* __restrict__ flags) {
  const int t = blockIdx.x;
  const int tid = threadIdx.x;
  __shared__ float cs[16], sn[16];
  if (tid < 16)       cs[tid]      = cosp[t * 16 + tid];
  else if (tid < 32)  sn[tid - 16] = sinp[t * 16 + tid - 16];
  __syncthreads();
  const int slot = slots[t];
  if (tid == 0) flags[slot] = 1u;
  ushort* qrow = qkv + (size_t)t * NQKV;
  float* kcr = kc + (size_t)slot * HIDN;
  float* vcr = vc + (size_t)slot * HIDN;

  for (int idx = tid; idx < 512; idx += 256) {
    int hh = idx >> 4, i = idx & 15;
    ushort* p = qrow + hh * DHEAD + i;
    float x1 = bf2f(p[0]), x2 = bf2f(p[16]);
    float c = cs[i], s = sn[i];
    p[0]  = f2bf(x1 * c - x2 * s);
    p[16] = f2bf(x1 * s + x2 * c);
  }
  for (int idx = tid; idx < 512; idx += 256) {
    int hh = idx >> 4, i = idx & 15;
    ushort* p = qrow + HIDN + hh * DHEAD + i;
    float x1 = bf2f(p[0]), x2 = bf2f(p[16]);
    float c = cs[i], s = sn[i];
    float k1 = x1 * c - x2 * s, k2 = x1 * s + x2 * c;
    p[0]  = f2bf(k1);
    p[16] = f2bf(k2);
    kcr[hh * DHEAD + i]      = k1;
    kcr[hh * DHEAD + i + 16] = k2;
  }
  for (int idx = tid; idx < 1536; idx += 256) {
    int hh = idx / 48, d = 32 + idx % 48;
    kcr[hh * DHEAD + d] = bf2f(qrow[HIDN + hh * DHEAD + d]);
  }
  for (int idx = tid; idx < HIDN; idx += 256) {
    vcr[idx] = bf2f(qrow[2 * HIDN + idx]);
  }
}

// ---- mega kernel: attn [0,1024) ∥ cache_fill [1024,5120) ∥ densew cvt -----
__global__ __launch_bounds__(512, 4)
void mega_kernel(const ushort* __restrict__ qkv, ushort* __restrict__ attn_out,
                 const float* __restrict__ kin, const float* __restrict__ vin,
                 const uint* __restrict__ flags,
                 float* __restrict__ kout, float* __restrict__ vout,
                 const float* __restrict__ densew, ushort* __restrict__ densewb) {
  __shared__ ushort lsK[64 * 104];
  __shared__ ushort lsVT[80 * 68];
  __shared__ ushort lsP[8][16 * 68];
  const int bid = blockIdx.x;

  if (bid >= 1024) {
    if (bid < 5120) {
      const int row = (bid - 1024) * 2 + (threadIdx.x >> 8);
      const int t2  = threadIdx.x & 255;
      if (flags[row]) return;
      const float4* ks = (const float4*)(kin + (size_t)row * HIDN);
      const float4* vs = (const float4*)(vin + (size_t)row * HIDN);
      float4* kd = (float4*)(kout + (size_t)row * HIDN);
      float4* vd = (float4*)(vout + (size_t)row * HIDN);
      for (int i = t2; i < HIDN / 4; i += 256) { kd[i] = ks[i]; vd[i] = vs[i]; }
    } else {
      int i = (bid - 5120) * 512 + threadIdx.x;
      for (; i < NQ_DW; i += 256 * 512) {
        float4 v = *(const float4*)(densew + i * 4);
        u16x4 o = { f2bf(v.x), f2bf(v.y), f2bf(v.z), f2bf(v.w) };
        *(u16x4*)(densewb + i * 4) = o;
      }
    }
    return;
  }

  const int qb = 7 - (bid >> 7);
  const int hb = bid & 127;
  const int h = hb & 31, b = hb >> 5;
  const int tid  = threadIdx.x;
  const int lane = tid & 63, w = tid >> 6;
  const int r    = lane & 15, g = lane >> 4;

  {
    int kv = tid >> 3, cp = tid & 7;
    *(uint*)&lsK[kv * 104 + 80 + cp * 2] = 0u;
  }

  const size_t qrow = (size_t)(b * SEQ + qb * 128 + w * 16 + r);
  const ushort* qp = qkv + qrow * NQKV + h * DHEAD;
  s16x8 qf[3];
  qf[0] = *(const s16x8*)(qp + g * 8);
  qf[1] = *(const s16x8*)(qp + 32 + g * 8);
  if (g < 2) qf[2] = *(const s16x8*)(qp + 64 + g * 8);
  else { s16x8 z = {0,0,0,0,0,0,0,0}; qf[2] = z; }

  int off_g[5]; uint off_kv[5];
#pragma unroll
  for (int j = 0; j < 5; j++) {
    int i = tid + j * 512;
    int kv = i / 40, dp = i - kv * 40;
    off_g[j]  = kv * NQKV + dp * 2;
    off_kv[j] = (uint)(kv * 104 + dp * 2) | ((uint)(dp * 2 * 68 + kv) << 16);
  }
  const ushort* kvbase = qkv + (size_t)(b * SEQ) * NQKV + HIDN + h * DHEAD;

  uint kreg[5], vreg[5];
#pragma unroll
  for (int j = 0; j < 5; j++) {
    kreg[j] = *(const uint*)(kvbase + off_g[j]);
    vreg[j] = *(const uint*)(kvbase + off_g[j] + HIDN);
  }

  float m_run[4] = {-1e30f, -1e30f, -1e30f, -1e30f};
  float l_run[4] = {0.f, 0.f, 0.f, 0.f};
  f32x4 acco[5];
#pragma unroll
  for (int nb = 0; nb < 5; nb++) { f32x4 z = {0.f,0.f,0.f,0.f}; acco[nb] = z; }

  const int ntiles = 2 * qb + 2;
  for (int t = 0; t < ntiles; t++) {
#pragma unroll
    for (int j = 0; j < 5; j++) {
      int ok = off_kv[j] & 0xffff, ov = off_kv[j] >> 16;
      *(uint*)&lsK[ok] = kreg[j];
      uint vv = vreg[j];
      lsVT[ov]      = (ushort)(vv & 0xffffu);
      lsVT[ov + 68] = (ushort)(vv >> 16);
    }
    __syncthreads();

    if (t + 1 < ntiles) {
      const ushort* nb_ = kvbase + (size_t)(t + 1) * 64 * NQKV;
#pragma unroll
      for (int j = 0; j < 5; j++) {
        kreg[j] = *(const uint*)(nb_ + off_g[j]);
        vreg[j] = *(const uint*)(nb_ + off_g[j] + HIDN);
      }
    }

    f32x4 sacc[4];
#pragma unroll
    for (int cb = 0; cb < 4; cb++) {
      f32x4 acc = {0.f, 0.f, 0.f, 0.f};
#pragma unroll
      for (int c = 0; c < 3; c++) {
        s16x8 kf = *(const s16x8*)&lsK[(cb * 16 + r) * 104 + c * 32 + g * 8];
        acc = mfma16(qf[c], kf, acc);
      }
      sacc[cb] = acc;
    }

    const bool diag = (t >= 2 * qb);
    const int kv0 = t * 64;
    const int q0  = qb * 128 + w * 16 + g * 4;
#pragma unroll
    for (int cb = 0; cb < 4; cb++)
#pragma unroll
      for (int j = 0; j < 4; j++) {
        float s = sacc[cb][j] * SCALE_F;
        if (diag && (kv0 + cb * 16 + r) > (q0 + j)) s = -1e30f;
        sacc[cb][j] = s;
      }

    float mnew[4], alpha[4], rs[4];
#pragma unroll
    for (int j = 0; j < 4; j++) {
      float m = fmaxf(fmaxf(sacc[0][j], sacc[1][j]), fmaxf(sacc[2][j], sacc[3][j]));
      m = fmaxf(m, __shfl_xor(m, 1));
      m = fmaxf(m, __shfl_xor(m, 2));
      m = fmaxf(m, __shfl_xor(m, 4));
      m = fmaxf(m, __shfl_xor(m, 8));
      mnew[j]  = fmaxf(m_run[j], m);
      alpha[j] = exp2f((m_run[j] - mnew[j]) * LOG2E_F);
      m_run[j] = mnew[j];
      rs[j] = 0.f;
    }

#pragma unroll
    for (int cb = 0; cb < 4; cb++)
#pragma unroll
      for (int j = 0; j < 4; j++) {
        float p = exp2f((sacc[cb][j] - mnew[j]) * LOG2E_F);
        rs[j] += p;
        lsP[w][(g * 4 + j) * 68 + cb * 16 + r] = f2bf(p);
      }

#pragma unroll
    for (int j = 0; j < 4; j++) {
      float v = rs[j];
      v += __shfl_xor(v, 1);
      v += __shfl_xor(v, 2);
      v += __shfl_xor(v, 4);
      v += __shfl_xor(v, 8);
      l_run[j] = l_run[j] * alpha[j] + v;
#pragma unroll
      for (int nb = 0; nb < 5; nb++) acco[nb][j] *= alpha[j];
    }

    s16x8 pa[2];
#pragma unroll
    for (int ch = 0; ch < 2; ch++) {
      s16x4 lo = *(const s16x4*)&lsP[w][r * 68 + ch * 32 + g * 8];
      s16x4 hi = *(const s16x4*)&lsP[w][r * 68 + ch * 32 + g * 8 + 4];
      pa[ch] = __builtin_shufflevector(lo, hi, 0, 1, 2, 3, 4, 5, 6, 7);
    }

#pragma unroll
    for (int nb = 0; nb < 5; nb++)
#pragma unroll
      for (int ch = 0; ch < 2; ch++) {
        s16x4 lo = *(const s16x4*)&lsVT[(nb * 16 + r) * 68 + ch * 32 + g * 8];
        s16x4 hi = *(const s16x4*)&lsVT[(nb * 16 + r) * 68 + ch * 32 + g * 8 + 4];
        s16x8 vf = __builtin_shufflevector(lo, hi, 0, 1, 2, 3, 4, 5, 6, 7);
        acco[nb] = mfma16(pa[ch], vf, acco[nb]);
      }

    __syncthreads();
  }

  const size_t orow = (size_t)(b * SEQ + qb * 128 + w * 16 + g * 4);
#pragma unroll
  for (int j = 0; j < 4; j++) {
    float inv = 1.0f / l_run[j];
#pragma unroll
    for (int nb = 0; nb < 5; nb++)
      attn_out[(orow + j) * HIDN + h * DHEAD + nb * 16 + r] = f2bf(acco[nb][j] * inv);
  }
}

// ---------------- launch ----------------
extern "C" void kernel_launch(void* const* d_in, const int* in_sizes, int n_in,
                              void* d_out, int out_size, void* d_ws, size_t ws_size,
                              hipStream_t stream) {
  (void)in_sizes; (void)n_in; (void)out_size; (void)ws_size;
  const float* hs      = (const float*)d_in[0];
  const float* cosp    = (const float*)d_in[1];
  const float* sinp    = (const float*)d_in[2];
  const int*   slots   = (const int*)  d_in[3];
  const float* kck_in  = (const float*)d_in[4];
  const float* kcv_in  = (const float*)d_in[5];
  const float* qkvw    = (const float*)d_in[6];
  const float* qkvb    = (const float*)d_in[7];
  const float* densew  = (const float*)d_in[8];
  const float* denseb  = (const float*)d_in[9];

  float* out    = (float*)d_out;
  float* kc_out = out + (size_t)TTOK * HIDN;
  float* vc_out = kc_out + (size_t)NSLOT * HIDN;

  char* ws = (char*)d_ws;
  ushort* hsb     = (ushort*)(ws);
  ushort* attnb   = (ushort*)(ws);               // aliases hsb (dead after gemm8p)
  ushort* qkvwb   = (ushort*)(ws + 20971520);
  ushort* densewb = (ushort*)(ws + 60293120);
  ushort* qkvb16  = (ushort*)(ws + 73400320);
  uint*   flags   = (uint*)(ws + 136314880);

  prep_kernel<<<2048, 256, 0, stream>>>(hs, qkvw, hsb, qkvwb, flags);

  gemm8p<1><<<480, 512, 0, stream>>>(hsb, qkvwb, qkvb, qkvb16, TTOK, NQKV, HIDN, 30, 4, 15);

  rope_scatter<<<TTOK, 256, 0, stream>>>(qkvb16, cosp, sinp, slots, kc_out, vc_out, flags);

  mega_kernel<<<5376, 512, 0, stream>>>(qkvb16, attnb, kck_in, kcv_in, flags,
                                        kc_out, vc_out, densew, densewb);

  // dense: 128^2 BK=32 double-buffered, 1 barrier/step, 640 blocks
  gemm_db32<<<640, 256, 0, stream>>>(
      attnb, densewb, denseb, out, TTOK, HIDN, HIDN, 20, 8, 10);
}